// Round 9
// baseline (699.022 us; speedup 1.0000x reference)
//
#include <hip/hip_runtime.h>
#include <hip/hip_fp16.h>
#include <math.h>

typedef float  f32x4 __attribute__((ext_vector_type(4)));
typedef unsigned short u16x8 __attribute__((ext_vector_type(8)));

#define NPTS 4096
#define DIM  512
#define BK   32
#define NTB  64
#define NTILES (NTB*(NTB+1)/2)       // 2080 upper-tri tiles

// ws layout (doubles)
#define WS_U_A   0
#define WS_U_B   4096
#define WS_PAB   8192
#define WS_PAA   (8192 + NTILES)
#define WS_PBB   (8192 + 2*NTILES)
#define WS_SQA   (8192 + 3*NTILES)
#define WS_SQB   (WS_SQA + NPTS)
#define WS_ZERO_DOUBLES WS_SQA

__device__ __forceinline__ void tri_decode(int t, int& bi, int& bj) {
  int r = (int)((sqrt(8.0 * (double)t + 1.0) - 1.0) * 0.5);
  while ((r + 1) * (r + 2) / 2 <= t) ++r;
  while (r * (r + 1) / 2 > t) --r;
  bj = r; bi = t - r * (r + 1) / 2;   // bi <= bj
}

// async global->LDS, 16 B per lane; LDS dest = uniform base + lane*16
__device__ __forceinline__ void gload16(const float* g, float* lds) {
  __builtin_amdgcn_global_load_lds(
      (const __attribute__((address_space(1))) void*)g,
      (__attribute__((address_space(3))) void*)lds, 16, 0, 0);
}

// ---------------- sq kernel: sq[i] = sum_k x[i][k]^2 (double) -------------
__global__ __launch_bounds__(256) void sq_kernel(const float* __restrict__ fa,
                                                 const float* __restrict__ fb,
                                                 double* __restrict__ ws) {
  int wave = threadIdx.x >> 6, lane = threadIdx.x & 63;
  int row = blockIdx.x * 4 + wave;
  const float* src = blockIdx.y ? fb : fa;
  double*      dst = blockIdx.y ? (ws + WS_SQB) : (ws + WS_SQA);
  const f32x4* p = (const f32x4*)(src + (size_t)row * DIM);
  double s = 0.0;
#pragma unroll
  for (int c = 0; c < DIM / 4 / 64; ++c) {
    f32x4 v = p[lane + c * 64];
    s += (double)v[0]*v[0] + (double)v[1]*v[1] + (double)v[2]*v[2] + (double)v[3]*v[3];
  }
  for (int off = 32; off; off >>= 1) s += __shfl_down(s, off);
  if (lane == 0) dst[row] = s;
}

// ---------------- fused gram + fp16 distances + all statistics ----------------
// 128 threads = 2 waves: wave0 -> matrix A, wave1 -> matrix B. 8x8 tile/thread.
// LDS: 4 panels [64 rows][32 k] linear (global_load_lds), k-slot XOR-swizzled by
// (row>>3)&7 via pre-swizzled GLOBAL source addresses; reads apply same XOR.
// NUMERICS FROZEN: per-(i,j) scalar fp32 fmaf chain, kk 0..31 ascending per
// BK=32 chunk (kk = 4g+k, g ascending), f64 flush per chunk, d2 = si+sj-2*accD,
// d = fp16_rne((float)sqrt(d2)), diagonal forced 0.
__attribute__((amdgpu_waves_per_eu(2, 2)))
__global__ void __launch_bounds__(128, 2)
gram_kernel(const float* __restrict__ fa, const float* __restrict__ fb,
            double* __restrict__ ws)
{
  int bi, bj; tri_decode(blockIdx.x, bi, bj);
  const int i0 = bi * 64, j0 = bj * 64;
  const bool diag = (bi == bj);

  __shared__ alignas(16) float smem[4 * 64 * BK];   // 32768 B: AI, AJ, BI, BJ
  __shared__ double wred[2][2];
  unsigned short* dbufB = (unsigned short*)smem;    // epilogue reuse (9216 B)

  const int t    = threadIdx.x;
  const int wave = t >> 6, lane = t & 63;
  const int lx   = lane & 7, ly = lane >> 3;
  const int lr   = lane >> 3, ls = lane & 7;        // staging row/slot

  float* ldsI = smem + (wave ? 2 : 0) * 2048;       // this wave's I panel
  float* ldsJ = smem + (wave ? 3 : 1) * 2048;       // this wave's J panel

  // per-lane global row bases for staging (row = base + idx*8 + lr)
  const float* gI = (wave ? fb : fa) + (size_t)(i0 + lr) * DIM;
  const float* gJ = (wave ? fb : fa) + (size_t)(j0 + lr) * DIM;

  float  acc[8][8];
  double accD[8][8];
#pragma unroll
  for (int m = 0; m < 8; ++m)
#pragma unroll
    for (int l = 0; l < 8; ++l) { acc[m][l] = 0.f; accD[m][l] = 0.0; }

#pragma unroll 1
  for (int k0 = 0; k0 < DIM; k0 += BK) {
    __syncthreads();   // previous chunk's reads done; LDS reusable
    // stage this chunk: 8 issues per panel, rows idx*8..idx*8+7, swizzled source
#pragma unroll
    for (int idx = 0; idx < 8; ++idx) {
      const int col = k0 + ((ls ^ idx) << 2);       // pre-swizzled k-slot
      gload16(gI + (size_t)idx * 8 * DIM + col, ldsI + idx * 256);
      gload16(gJ + (size_t)idx * 8 * DIM + col, ldsJ + idx * 256);
    }
    __syncthreads();   // compiler drains vmcnt(0) before barrier -> data landed

#pragma unroll 2
    for (int g = 0; g < 8; ++g) {
      f32x4 vI[8];
      const float* baseI = ldsI + ((g ^ ly) << 2);
#pragma unroll
      for (int m = 0; m < 8; ++m)
        vI[m] = *(const f32x4*)(baseI + (ly * 8 + m) * 32);
      const float* baseJ = ldsJ + ((g ^ lx) << 2);
#pragma unroll
      for (int h = 0; h < 2; ++h) {
        f32x4 vJ[4];
#pragma unroll
        for (int l = 0; l < 4; ++l)
          vJ[l] = *(const f32x4*)(baseJ + (lx * 8 + h * 4 + l) * 32);
#pragma unroll
        for (int kk = 0; kk < 4; ++kk)
#pragma unroll
          for (int m = 0; m < 8; ++m)
#pragma unroll
            for (int l = 0; l < 4; ++l)
              acc[m][h * 4 + l] = fmaf(vI[m][kk], vJ[l][kk], acc[m][h * 4 + l]);
      }
    }
    // f64 flush per BK chunk (frozen cadence)
#pragma unroll
    for (int m = 0; m < 8; ++m)
#pragma unroll
      for (int l = 0; l < 8; ++l) {
        accD[m][l] += (double)acc[m][l];
        acc[m][l] = 0.f;
      }
  }

  __syncthreads();   // staging LDS dead; safe to reuse as dbufB

  // ---- distances (fp16-quantized) + per-thread stats ----
  const double* sqx = ws + (wave ? WS_SQB : WS_SQA);
  double*       ux  = ws + (wave ? WS_U_B : WS_U_A);

  double si[8], sj[8];
#pragma unroll
  for (int m = 0; m < 8; ++m) si[m] = sqx[i0 + ly * 8 + m];
#pragma unroll
  for (int l = 0; l < 8; ++l) sj[l] = sqx[j0 + lx * 8 + l];

  double rs[8] = {0,0,0,0,0,0,0,0}, cs[8] = {0,0,0,0,0,0,0,0};
  double self = 0.0;
  u16x8 pk[8];
#pragma unroll
  for (int m = 0; m < 8; ++m) {
#pragma unroll
    for (int l = 0; l < 8; ++l) {
      double d2 = si[m] + sj[l] - 2.0 * accD[m][l];
      unsigned short bits = 0;
      double dq = 0.0;
      if (d2 > 0.0) {
        float df = (float)sqrt(d2);
        __half h = __float2half(df);          // RNE — frozen quantization
        bits = __half_as_ushort(h);
        dq = (double)__half2float(h);
      }
      if (diag && (ly * 8 + m == lx * 8 + l)) { bits = 0; dq = 0.0; }
      pk[m][l] = bits;
      rs[m] += dq;
      cs[l] += dq;
      self  += dq * dq;
    }
  }
  if (wave == 1) {
#pragma unroll
    for (int m = 0; m < 8; ++m)
      *(u16x8*)(dbufB + (size_t)(ly * 8 + m) * 72 + lx * 8) = pk[m];
  }

  // row sums -> u[i0+row] (reduce over lx: xor 1,2,4 — tree identical to prior rounds)
#pragma unroll
  for (int m = 0; m < 8; ++m) {
    double v = rs[m];
    v += __shfl_xor(v, 1); v += __shfl_xor(v, 2); v += __shfl_xor(v, 4);
    if (lx == 0) atomicAdd(&ux[i0 + ly * 8 + m], v);
  }
  if (!diag) {  // transposed entries: col sums -> u[j0+col] (reduce over ly)
#pragma unroll
    for (int l = 0; l < 8; ++l) {
      double v = cs[l];
      v += __shfl_xor(v, 8); v += __shfl_xor(v, 16); v += __shfl_xor(v, 32);
      if (ly == 0) atomicAdd(&ux[j0 + lx * 8 + l], v);
    }
  }

  __syncthreads();   // dbufB fully written

  double pab = 0.0;
  if (wave == 0) {
#pragma unroll
    for (int m = 0; m < 8; ++m) {
      u16x8 db = *(const u16x8*)(dbufB + (size_t)(ly * 8 + m) * 72 + lx * 8);
#pragma unroll
      for (int l = 0; l < 8; ++l)
        pab += (double)__half2float(__ushort_as_half(pk[m][l]))
             * (double)__half2float(__ushort_as_half(db[l]));
    }
  }

  for (int off = 32; off; off >>= 1) {
    pab  += __shfl_down(pab, off);
    self += __shfl_down(self, off);
  }
  if (lane == 0) {
    wred[wave][0] = (wave == 0) ? pab  : self;   // wave0: pab, wave1: pbb
    wred[wave][1] = (wave == 0) ? self : 0.0;    // wave0: paa
  }
  __syncthreads();
  if (t == 0) {
    double w = diag ? 1.0 : 2.0;
    ws[WS_PAB + blockIdx.x] = w * wred[0][0];
    ws[WS_PAA + blockIdx.x] = w * wred[0][1];
    ws[WS_PBB + blockIdx.x] = w * wred[1][0];
  }
}

// ---------------- final: reduce stats, closed-form U-centered dots --------------------
__global__ __launch_bounds__(256) void final_kernel(const double* __restrict__ ws,
                                                    float* __restrict__ out)
{
  const int t = threadIdx.x;
  double sa = 0, sb = 0, uab = 0, uaa = 0, ubb = 0, ab = 0, aa = 0, bb = 0;
  for (int i = t; i < NPTS; i += 256) {
    double a = ws[WS_U_A + i], b = ws[WS_U_B + i];
    sa += a; sb += b; uab += a * b; uaa += a * a; ubb += b * b;
  }
  for (int i = t; i < NTILES; i += 256) {
    ab += ws[WS_PAB + i]; aa += ws[WS_PAA + i]; bb += ws[WS_PBB + i];
  }
  for (int off = 32; off; off >>= 1) {
    sa  += __shfl_down(sa, off);  sb  += __shfl_down(sb, off);
    uab += __shfl_down(uab, off); uaa += __shfl_down(uaa, off); ubb += __shfl_down(ubb, off);
    ab  += __shfl_down(ab, off);  aa  += __shfl_down(aa, off);  bb  += __shfl_down(bb, off);
  }
  __shared__ double red[4][8];
  int wave = t >> 6, lane = t & 63;
  if (lane == 0) {
    red[wave][0] = sa;  red[wave][1] = sb;  red[wave][2] = uab; red[wave][3] = uaa;
    red[wave][4] = ubb; red[wave][5] = ab;  red[wave][6] = aa;  red[wave][7] = bb;
  }
  __syncthreads();
  if (t == 0) {
    double v[8] = {0,0,0,0,0,0,0,0};
    for (int q = 0; q < 4; ++q) for (int z = 0; z < 8; ++z) v[z] += red[q][z];
    const double SA = v[0], SB = v[1], UAB = v[2], UAA = v[3], UBB = v[4];
    const double PAB = v[5], PAA = v[6], PBB = v[7];
    const double n = (double)NPTS, nm2 = n - 2.0;
    auto dotv = [&](double P, double U, double sx, double sy) {
      double tX = sx / ((n - 1.0) * nm2), tY = sy / ((n - 1.0) * nm2);
      double RX = sx / nm2, RY = sy / nm2;
      double su  = U / nm2;
      double srr = U / (nm2 * nm2);
      double full = P - 4.0 * su + tY * sx + tX * sy + 2.0 * n * srr + 2.0 * RX * RY
                  - 2.0 * n * tY * RX - 2.0 * n * tX * RY + n * n * tX * tY;
      double dg = n * tX * tY - 2.0 * tX * RY - 2.0 * tY * RX + 4.0 * srr;
      return full - dg;
    };
    const double denomc = n * (n - 3.0);
    double dab = dotv(PAB, UAB, SA, SB) / denomc;
    double daa = dotv(PAA, UAA, SA, SA) / denomc;
    double dbb = dotv(PBB, UBB, SB, SB) / denomc;
    double dn = sqrt(daa * dbb);
    if (dn < 1e-9) dn = 1e-9;
    out[0] = (float)(dab / dn);
  }
}

extern "C" void kernel_launch(void* const* d_in, const int* in_sizes, int n_in,
                              void* d_out, int out_size, void* d_ws, size_t ws_size,
                              hipStream_t stream) {
  const float* fa = (const float*)d_in[0];
  const float* fb = (const float*)d_in[1];
  double* ws = (double*)d_ws;

  hipMemsetAsync(d_ws, 0, WS_ZERO_DOUBLES * sizeof(double), stream);
  sq_kernel<<<dim3(NPTS / 4, 2), 256, 0, stream>>>(fa, fb, ws);
  gram_kernel<<<NTILES, 128, 0, stream>>>(fa, fb, ws);
  final_kernel<<<1, 256, 0, stream>>>(ws, (float*)d_out);
}

// Round 10
// 641.965 us; speedup vs baseline: 1.0889x; 1.0889x over previous
//
#include <hip/hip_runtime.h>
#include <hip/hip_fp16.h>
#include <math.h>

typedef float  f32x4 __attribute__((ext_vector_type(4)));
typedef unsigned short u16x8 __attribute__((ext_vector_type(8)));

#define NPTS 4096
#define DIM  512
#define BK   32
#define NTB  64
#define NTILES (NTB*(NTB+1)/2)       // 2080 upper-tri tiles

// ws layout (doubles)
#define WS_U_A   0
#define WS_U_B   4096
#define WS_PAB   8192
#define WS_PAA   (8192 + NTILES)
#define WS_PBB   (8192 + 2*NTILES)
#define WS_SQA   (8192 + 3*NTILES)
#define WS_SQB   (WS_SQA + NPTS)
#define WS_ZERO_DOUBLES WS_SQA

__device__ __forceinline__ void tri_decode(int t, int& bi, int& bj) {
  int r = (int)((sqrt(8.0 * (double)t + 1.0) - 1.0) * 0.5);
  while ((r + 1) * (r + 2) / 2 <= t) ++r;
  while (r * (r + 1) / 2 > t) --r;
  bj = r; bi = t - r * (r + 1) / 2;   // bi <= bj
}

// async global->LDS, 16 B per lane; LDS dest = wave-uniform base + lane*16
__device__ __forceinline__ void gload16(const float* g, float* lds) {
  __builtin_amdgcn_global_load_lds(
      (const __attribute__((address_space(1))) void*)g,
      (__attribute__((address_space(3))) void*)lds, 16, 0, 0);
}

// ---------------- sq kernel: sq[i] = sum_k x[i][k]^2 (double) -------------
__global__ __launch_bounds__(256) void sq_kernel(const float* __restrict__ fa,
                                                 const float* __restrict__ fb,
                                                 double* __restrict__ ws) {
  int wave = threadIdx.x >> 6, lane = threadIdx.x & 63;
  int row = blockIdx.x * 4 + wave;
  const float* src = blockIdx.y ? fb : fa;
  double*      dst = blockIdx.y ? (ws + WS_SQB) : (ws + WS_SQA);
  const f32x4* p = (const f32x4*)(src + (size_t)row * DIM);
  double s = 0.0;
#pragma unroll
  for (int c = 0; c < DIM / 4 / 64; ++c) {
    f32x4 v = p[lane + c * 64];
    s += (double)v[0]*v[0] + (double)v[1]*v[1] + (double)v[2]*v[2] + (double)v[3]*v[3];
  }
  for (int off = 32; off; off >>= 1) s += __shfl_down(s, off);
  if (lane == 0) dst[row] = s;
}

// ---------------- fused gram + fp16 distances + all statistics ----------------
// 128 threads = 2 waves: wave0 -> matrix A, wave1 -> matrix B. 8x8 tile/thread.
// LDS: double-buffered 4 panels [64 rows][32 k] LINEAR (global_load_lds direct,
// no swizzle -- round 9 measured SQ_LDS_BANK_CONFLICT=0 for this read pattern).
// m97 schedule: issue chunk c+1 loads into idle buffer, compute chunk c,
// ONE barrier per chunk (vmcnt drain free: loads land under 2048 FMAs).
// NUMERICS FROZEN: per-(i,j) scalar fp32 fmaf chain, kk 0..31 ascending per
// BK=32 chunk (kk = 4g+k, g ascending -- round 9 proved bit-identical),
// f64 flush per chunk, d2 = si+sj-2*accD, d = fp16_rne((float)sqrt(d2)),
// diagonal forced 0.
__global__ void __launch_bounds__(128, 1)
gram_kernel(const float* __restrict__ fa, const float* __restrict__ fb,
            double* __restrict__ ws)
{
  int bi, bj; tri_decode(blockIdx.x, bi, bj);
  const int i0 = bi * 64, j0 = bj * 64;
  const bool diag = (bi == bj);

  __shared__ alignas(16) float smem[2 * 4 * 64 * BK];   // 65536 B: dbuf x {AI,AJ,BI,BJ}
  __shared__ double wred[2][2];
  unsigned short* dbufB = (unsigned short*)smem;        // epilogue reuse (9216 B)

  const int t    = threadIdx.x;
  const int wave = t >> 6, lane = t & 63;
  const int lx   = lane & 7, ly = lane >> 3;

  // per-lane global staging pointers: lane L covers row (L>>3), k-block (L&7)
  const float* gbase = wave ? fb : fa;
  const float* gIl = gbase + (size_t)(i0 + (lane >> 3)) * DIM + ((lane & 7) << 2);
  const float* gJl = gbase + (size_t)(j0 + (lane >> 3)) * DIM + ((lane & 7) << 2);

  float  acc[8][8];
  double accD[8][8];
#pragma unroll
  for (int m = 0; m < 8; ++m)
#pragma unroll
    for (int l = 0; l < 8; ++l) { acc[m][l] = 0.f; accD[m][l] = 0.0; }

  // prologue: stage chunk 0 into buffer 0
  {
    float* LI = smem + (wave ? 4096 : 0);
    float* LJ = LI + 2048;
#pragma unroll
    for (int p = 0; p < 8; ++p) {
      gload16(gIl + (size_t)p * 8 * DIM, LI + p * 256);
      gload16(gJl + (size_t)p * 8 * DIM, LJ + p * 256);
    }
  }
  __syncthreads();   // drain vmcnt: chunk 0 landed

#pragma unroll 2
  for (int c = 0; c < 16; ++c) {
    const float* cb = smem + ((c & 1) ? 8192 : 0) + (wave ? 4096 : 0);
    // prefetch chunk c+1 into the idle buffer (async, hides under compute)
    if (c < 15) {
      float* nb = smem + (((c + 1) & 1) ? 8192 : 0) + (wave ? 4096 : 0);
      const int kn = (c + 1) * BK;
#pragma unroll
      for (int p = 0; p < 8; ++p) {
        gload16(gIl + (size_t)p * 8 * DIM + kn, nb + p * 256);
        gload16(gJl + (size_t)p * 8 * DIM + kn, nb + 2048 + p * 256);
      }
    }
    const float* ldsI = cb + ly * 256;        // this thread's I rows
    const float* ldsJ = cb + 2048 + lx * 256; // this thread's J rows

#pragma unroll 1
    for (int g = 0; g < 8; ++g) {
      f32x4 vI[8];
#pragma unroll
      for (int m = 0; m < 8; ++m)
        vI[m] = *(const f32x4*)(ldsI + m * 32 + (g << 2));
#pragma unroll
      for (int h = 0; h < 2; ++h) {
        f32x4 vJ[4];
#pragma unroll
        for (int l = 0; l < 4; ++l)
          vJ[l] = *(const f32x4*)(ldsJ + (h * 4 + l) * 32 + (g << 2));
#pragma unroll
        for (int kk = 0; kk < 4; ++kk)
#pragma unroll
          for (int m = 0; m < 8; ++m)
#pragma unroll
            for (int l = 0; l < 4; ++l)
              acc[m][h * 4 + l] = fmaf(vI[m][kk], vJ[l][kk], acc[m][h * 4 + l]);
      }
    }
    // f64 flush per BK chunk (frozen cadence)
#pragma unroll
    for (int m = 0; m < 8; ++m)
#pragma unroll
      for (int l = 0; l < 8; ++l) {
        accD[m][l] += (double)acc[m][l];
        acc[m][l] = 0.f;
      }
    __syncthreads();   // chunk c reads done everywhere; chunk c+1 loads drained
  }

  // ---- distances (fp16-quantized) + per-thread stats ----
  const double* sqx = ws + (wave ? WS_SQB : WS_SQA);
  double*       ux  = ws + (wave ? WS_U_B : WS_U_A);

  double si[8], sj[8];
#pragma unroll
  for (int m = 0; m < 8; ++m) si[m] = sqx[i0 + ly * 8 + m];
#pragma unroll
  for (int l = 0; l < 8; ++l) sj[l] = sqx[j0 + lx * 8 + l];

  double rs[8] = {0,0,0,0,0,0,0,0}, cs[8] = {0,0,0,0,0,0,0,0};
  double self = 0.0;
  u16x8 pk[8];
#pragma unroll
  for (int m = 0; m < 8; ++m) {
#pragma unroll
    for (int l = 0; l < 8; ++l) {
      double d2 = si[m] + sj[l] - 2.0 * accD[m][l];
      unsigned short bits = 0;
      double dq = 0.0;
      if (d2 > 0.0) {
        float df = (float)sqrt(d2);
        __half h = __float2half(df);          // RNE -- frozen quantization
        bits = __half_as_ushort(h);
        dq = (double)__half2float(h);
      }
      if (diag && (ly * 8 + m == lx * 8 + l)) { bits = 0; dq = 0.0; }
      pk[m][l] = bits;
      rs[m] += dq;
      cs[l] += dq;
      self  += dq * dq;
    }
  }
  if (wave == 1) {
#pragma unroll
    for (int m = 0; m < 8; ++m)
      *(u16x8*)(dbufB + (size_t)(ly * 8 + m) * 72 + lx * 8) = pk[m];
  }

  // row sums -> u[i0+row] (reduce over lx: xor 1,2,4 -- tree identical to prior rounds)
#pragma unroll
  for (int m = 0; m < 8; ++m) {
    double v = rs[m];
    v += __shfl_xor(v, 1); v += __shfl_xor(v, 2); v += __shfl_xor(v, 4);
    if (lx == 0) atomicAdd(&ux[i0 + ly * 8 + m], v);
  }
  if (!diag) {  // transposed entries: col sums -> u[j0+col] (reduce over ly)
#pragma unroll
    for (int l = 0; l < 8; ++l) {
      double v = cs[l];
      v += __shfl_xor(v, 8); v += __shfl_xor(v, 16); v += __shfl_xor(v, 32);
      if (ly == 0) atomicAdd(&ux[j0 + lx * 8 + l], v);
    }
  }

  __syncthreads();   // dbufB fully written

  double pab = 0.0;
  if (wave == 0) {
#pragma unroll
    for (int m = 0; m < 8; ++m) {
      u16x8 db = *(const u16x8*)(dbufB + (size_t)(ly * 8 + m) * 72 + lx * 8);
#pragma unroll
      for (int l = 0; l < 8; ++l)
        pab += (double)__half2float(__ushort_as_half(pk[m][l]))
             * (double)__half2float(__ushort_as_half(db[l]));
    }
  }

  for (int off = 32; off; off >>= 1) {
    pab  += __shfl_down(pab, off);
    self += __shfl_down(self, off);
  }
  if (lane == 0) {
    wred[wave][0] = (wave == 0) ? pab  : self;   // wave0: pab, wave1: pbb
    wred[wave][1] = (wave == 0) ? self : 0.0;    // wave0: paa
  }
  __syncthreads();
  if (t == 0) {
    double w = diag ? 1.0 : 2.0;
    ws[WS_PAB + blockIdx.x] = w * wred[0][0];
    ws[WS_PAA + blockIdx.x] = w * wred[0][1];
    ws[WS_PBB + blockIdx.x] = w * wred[1][0];
  }
}

// ---------------- final: reduce stats, closed-form U-centered dots --------------------
__global__ __launch_bounds__(256) void final_kernel(const double* __restrict__ ws,
                                                    float* __restrict__ out)
{
  const int t = threadIdx.x;
  double sa = 0, sb = 0, uab = 0, uaa = 0, ubb = 0, ab = 0, aa = 0, bb = 0;
  for (int i = t; i < NPTS; i += 256) {
    double a = ws[WS_U_A + i], b = ws[WS_U_B + i];
    sa += a; sb += b; uab += a * b; uaa += a * a; ubb += b * b;
  }
  for (int i = t; i < NTILES; i += 256) {
    ab += ws[WS_PAB + i]; aa += ws[WS_PAA + i]; bb += ws[WS_PBB + i];
  }
  for (int off = 32; off; off >>= 1) {
    sa  += __shfl_down(sa, off);  sb  += __shfl_down(sb, off);
    uab += __shfl_down(uab, off); uaa += __shfl_down(uaa, off); ubb += __shfl_down(ubb, off);
    ab  += __shfl_down(ab, off);  aa  += __shfl_down(aa, off);  bb  += __shfl_down(bb, off);
  }
  __shared__ double red[4][8];
  int wave = t >> 6, lane = t & 63;
  if (lane == 0) {
    red[wave][0] = sa;  red[wave][1] = sb;  red[wave][2] = uab; red[wave][3] = uaa;
    red[wave][4] = ubb; red[wave][5] = ab;  red[wave][6] = aa;  red[wave][7] = bb;
  }
  __syncthreads();
  if (t == 0) {
    double v[8] = {0,0,0,0,0,0,0,0};
    for (int q = 0; q < 4; ++q) for (int z = 0; z < 8; ++z) v[z] += red[q][z];
    const double SA = v[0], SB = v[1], UAB = v[2], UAA = v[3], UBB = v[4];
    const double PAB = v[5], PAA = v[6], PBB = v[7];
    const double n = (double)NPTS, nm2 = n - 2.0;
    auto dotv = [&](double P, double U, double sx, double sy) {
      double tX = sx / ((n - 1.0) * nm2), tY = sy / ((n - 1.0) * nm2);
      double RX = sx / nm2, RY = sy / nm2;
      double su  = U / nm2;
      double srr = U / (nm2 * nm2);
      double full = P - 4.0 * su + tY * sx + tX * sy + 2.0 * n * srr + 2.0 * RX * RY
                  - 2.0 * n * tY * RX - 2.0 * n * tX * RY + n * n * tX * tY;
      double dg = n * tX * tY - 2.0 * tX * RY - 2.0 * tY * RX + 4.0 * srr;
      return full - dg;
    };
    const double denomc = n * (n - 3.0);
    double dab = dotv(PAB, UAB, SA, SB) / denomc;
    double daa = dotv(PAA, UAA, SA, SA) / denomc;
    double dbb = dotv(PBB, UBB, SB, SB) / denomc;
    double dn = sqrt(daa * dbb);
    if (dn < 1e-9) dn = 1e-9;
    out[0] = (float)(dab / dn);
  }
}

extern "C" void kernel_launch(void* const* d_in, const int* in_sizes, int n_in,
                              void* d_out, int out_size, void* d_ws, size_t ws_size,
                              hipStream_t stream) {
  const float* fa = (const float*)d_in[0];
  const float* fb = (const float*)d_in[1];
  double* ws = (double*)d_ws;

  hipMemsetAsync(d_ws, 0, WS_ZERO_DOUBLES * sizeof(double), stream);
  sq_kernel<<<dim3(NPTS / 4, 2), 256, 0, stream>>>(fa, fb, ws);
  gram_kernel<<<NTILES, 128, 0, stream>>>(fa, fb, ws);
  final_kernel<<<1, 256, 0, stream>>>(ws, (float*)d_out);
}

// Round 11
// 534.511 us; speedup vs baseline: 1.3078x; 1.2010x over previous
//
#include <hip/hip_runtime.h>
#include <hip/hip_fp16.h>
#include <math.h>

typedef float  f32x4 __attribute__((ext_vector_type(4)));
typedef unsigned short u16x8 __attribute__((ext_vector_type(8)));

#define NPTS 4096
#define DIM  512
#define BK   32
#define NTB  64
#define NTILES (NTB*(NTB+1)/2)       // 2080 upper-tri tiles

// ws layout (doubles)
#define WS_U_A   0
#define WS_U_B   4096
#define WS_PAB   8192
#define WS_PAA   (8192 + NTILES)
#define WS_PBB   (8192 + 2*NTILES)
#define WS_SQA   (8192 + 3*NTILES)
#define WS_SQB   (WS_SQA + NPTS)
#define WS_ZERO_DOUBLES WS_SQA

__device__ __forceinline__ void tri_decode(int t, int& bi, int& bj) {
  int r = (int)((sqrt(8.0 * (double)t + 1.0) - 1.0) * 0.5);
  while ((r + 1) * (r + 2) / 2 <= t) ++r;
  while (r * (r + 1) / 2 > t) --r;
  bj = r; bi = t - r * (r + 1) / 2;   // bi <= bj
}

// async global->LDS, 16 B per lane; LDS dest = wave-uniform base + lane*16
__device__ __forceinline__ void gload16(const float* g, float* lds) {
  __builtin_amdgcn_global_load_lds(
      (const __attribute__((address_space(1))) void*)g,
      (__attribute__((address_space(3))) void*)lds, 16, 0, 0);
}

// ---------------- sq kernel: sq[i] = sum_k x[i][k]^2 (double) -------------
__global__ __launch_bounds__(256) void sq_kernel(const float* __restrict__ fa,
                                                 const float* __restrict__ fb,
                                                 double* __restrict__ ws) {
  int wave = threadIdx.x >> 6, lane = threadIdx.x & 63;
  int row = blockIdx.x * 4 + wave;
  const float* src = blockIdx.y ? fb : fa;
  double*      dst = blockIdx.y ? (ws + WS_SQB) : (ws + WS_SQA);
  const f32x4* p = (const f32x4*)(src + (size_t)row * DIM);
  double s = 0.0;
#pragma unroll
  for (int c = 0; c < DIM / 4 / 64; ++c) {
    f32x4 v = p[lane + c * 64];
    s += (double)v[0]*v[0] + (double)v[1]*v[1] + (double)v[2]*v[2] + (double)v[3]*v[3];
  }
  for (int off = 32; off; off >>= 1) s += __shfl_down(s, off);
  if (lane == 0) dst[row] = s;
}

// ---------------- fused gram + fp16 distances + all statistics ----------------
// 128 threads = 2 waves: wave0 -> matrix A, wave1 -> matrix B. 8x8 tile/thread.
// LDS: double-buffered 4 panels [64 rows][32 k], XOR-swizzled k-slots:
//   LDS slot s of row-group p holds global k-slot (s ^ p). Achieved by
//   pre-swizzling the per-lane GLOBAL source column (dest stays linear, as
//   global_load_lds requires); reads apply the same XOR. Round 9 measured
//   SQ_LDS_BANK_CONFLICT = 0 for this exact pattern; round 10 measured 1.7e8
//   without it (8-way: row stride 128 B == bank-group aliasing).
// m97 schedule (round 10, validated): issue chunk c+1 loads into idle buffer,
// compute chunk c, one barrier per chunk.
// NUMERICS FROZEN: per-(i,j) scalar fp32 fmaf chain, kk = 4g+k, g ascending
// 0..7, k 0..3 (bit-identical rounds 9/10), f64 flush per BK=32 chunk,
// d2 = si+sj-2*accD, d = fp16_rne((float)sqrt(d2)), diagonal forced 0.
__global__ void __launch_bounds__(128, 1)
gram_kernel(const float* __restrict__ fa, const float* __restrict__ fb,
            double* __restrict__ ws)
{
  int bi, bj; tri_decode(blockIdx.x, bi, bj);
  const int i0 = bi * 64, j0 = bj * 64;
  const bool diag = (bi == bj);

  __shared__ alignas(16) float smem[2 * 4 * 64 * BK];   // 65536 B: dbuf x {AI,AJ,BI,BJ}
  __shared__ double wred[2][2];
  unsigned short* dbufB = (unsigned short*)smem;        // epilogue reuse (9216 B)

  const int t    = threadIdx.x;
  const int wave = t >> 6, lane = t & 63;
  const int lx   = lane & 7, ly = lane >> 3;
  const int lr   = lane >> 3;                 // staging row within group
  const int ls4  = (lane & 7) << 2;           // staging k-slot byte/4 offset

  // per-lane global ROW bases for staging (slot offset applied per issue, swizzled)
  const float* gbase = wave ? fb : fa;
  const float* gIr = gbase + (size_t)(i0 + lr) * DIM;
  const float* gJr = gbase + (size_t)(j0 + lr) * DIM;

  float  acc[8][8];
  double accD[8][8];
#pragma unroll
  for (int m = 0; m < 8; ++m)
#pragma unroll
    for (int l = 0; l < 8; ++l) { acc[m][l] = 0.f; accD[m][l] = 0.0; }

  // prologue: stage chunk 0 into buffer 0 (source column swizzled: slot = ls ^ p)
  {
    float* LI = smem + (wave ? 4096 : 0);
    float* LJ = LI + 2048;
#pragma unroll
    for (int p = 0; p < 8; ++p) {
      const int col = ls4 ^ (p << 2);
      gload16(gIr + (size_t)p * 8 * DIM + col, LI + p * 256);
      gload16(gJr + (size_t)p * 8 * DIM + col, LJ + p * 256);
    }
  }
  __syncthreads();   // drain vmcnt: chunk 0 landed

#pragma unroll 2
  for (int c = 0; c < 16; ++c) {
    const float* cb = smem + ((c & 1) ? 8192 : 0) + (wave ? 4096 : 0);
    // prefetch chunk c+1 into the idle buffer (async, hides under compute)
    if (c < 15) {
      float* nb = smem + (((c + 1) & 1) ? 8192 : 0) + (wave ? 4096 : 0);
      const int kn = (c + 1) * BK;
#pragma unroll
      for (int p = 0; p < 8; ++p) {
        const int col = kn + (ls4 ^ (p << 2));
        gload16(gIr + (size_t)p * 8 * DIM + col, nb + p * 256);
        gload16(gJr + (size_t)p * 8 * DIM + col, nb + 2048 + p * 256);
      }
    }
    const float* ldsI = cb + ly * 256;        // this thread's I row-group (p = ly)
    const float* ldsJ = cb + 2048 + lx * 256; // this thread's J row-group (p = lx)

#pragma unroll 1
    for (int g = 0; g < 8; ++g) {
      const int offI = (g << 2) ^ (ly << 2);  // de-swizzle: slot g of group ly
      const int offJ = (g << 2) ^ (lx << 2);
      f32x4 vI[8];
#pragma unroll
      for (int m = 0; m < 8; ++m)
        vI[m] = *(const f32x4*)(ldsI + m * 32 + offI);
#pragma unroll
      for (int h = 0; h < 2; ++h) {
        f32x4 vJ[4];
#pragma unroll
        for (int l = 0; l < 4; ++l)
          vJ[l] = *(const f32x4*)(ldsJ + (h * 4 + l) * 32 + offJ);
#pragma unroll
        for (int kk = 0; kk < 4; ++kk)
#pragma unroll
          for (int m = 0; m < 8; ++m)
#pragma unroll
            for (int l = 0; l < 4; ++l)
              acc[m][h * 4 + l] = fmaf(vI[m][kk], vJ[l][kk], acc[m][h * 4 + l]);
      }
    }
    // f64 flush per BK chunk (frozen cadence)
#pragma unroll
    for (int m = 0; m < 8; ++m)
#pragma unroll
      for (int l = 0; l < 8; ++l) {
        accD[m][l] += (double)acc[m][l];
        acc[m][l] = 0.f;
      }
    __syncthreads();   // chunk c reads done everywhere; chunk c+1 loads drained
  }

  // ---- distances (fp16-quantized) + per-thread stats ----
  const double* sqx = ws + (wave ? WS_SQB : WS_SQA);
  double*       ux  = ws + (wave ? WS_U_B : WS_U_A);

  double si[8], sj[8];
#pragma unroll
  for (int m = 0; m < 8; ++m) si[m] = sqx[i0 + ly * 8 + m];
#pragma unroll
  for (int l = 0; l < 8; ++l) sj[l] = sqx[j0 + lx * 8 + l];

  double rs[8] = {0,0,0,0,0,0,0,0}, cs[8] = {0,0,0,0,0,0,0,0};
  double self = 0.0;
  u16x8 pk[8];
#pragma unroll
  for (int m = 0; m < 8; ++m) {
#pragma unroll
    for (int l = 0; l < 8; ++l) {
      double d2 = si[m] + sj[l] - 2.0 * accD[m][l];
      unsigned short bits = 0;
      double dq = 0.0;
      if (d2 > 0.0) {
        float df = (float)sqrt(d2);
        __half h = __float2half(df);          // RNE -- frozen quantization
        bits = __half_as_ushort(h);
        dq = (double)__half2float(h);
      }
      if (diag && (ly * 8 + m == lx * 8 + l)) { bits = 0; dq = 0.0; }
      pk[m][l] = bits;
      rs[m] += dq;
      cs[l] += dq;
      self  += dq * dq;
    }
  }
  if (wave == 1) {
#pragma unroll
    for (int m = 0; m < 8; ++m)
      *(u16x8*)(dbufB + (size_t)(ly * 8 + m) * 72 + lx * 8) = pk[m];
  }

  // row sums -> u[i0+row] (reduce over lx: xor 1,2,4 -- tree identical to prior rounds)
#pragma unroll
  for (int m = 0; m < 8; ++m) {
    double v = rs[m];
    v += __shfl_xor(v, 1); v += __shfl_xor(v, 2); v += __shfl_xor(v, 4);
    if (lx == 0) atomicAdd(&ux[i0 + ly * 8 + m], v);
  }
  if (!diag) {  // transposed entries: col sums -> u[j0+col] (reduce over ly)
#pragma unroll
    for (int l = 0; l < 8; ++l) {
      double v = cs[l];
      v += __shfl_xor(v, 8); v += __shfl_xor(v, 16); v += __shfl_xor(v, 32);
      if (ly == 0) atomicAdd(&ux[j0 + lx * 8 + l], v);
    }
  }

  __syncthreads();   // dbufB fully written

  double pab = 0.0;
  if (wave == 0) {
#pragma unroll
    for (int m = 0; m < 8; ++m) {
      u16x8 db = *(const u16x8*)(dbufB + (size_t)(ly * 8 + m) * 72 + lx * 8);
#pragma unroll
      for (int l = 0; l < 8; ++l)
        pab += (double)__half2float(__ushort_as_half(pk[m][l]))
             * (double)__half2float(__ushort_as_half(db[l]));
    }
  }

  for (int off = 32; off; off >>= 1) {
    pab  += __shfl_down(pab, off);
    self += __shfl_down(self, off);
  }
  if (lane == 0) {
    wred[wave][0] = (wave == 0) ? pab  : self;   // wave0: pab, wave1: pbb
    wred[wave][1] = (wave == 0) ? self : 0.0;    // wave0: paa
  }
  __syncthreads();
  if (t == 0) {
    double w = diag ? 1.0 : 2.0;
    ws[WS_PAB + blockIdx.x] = w * wred[0][0];
    ws[WS_PAA + blockIdx.x] = w * wred[0][1];
    ws[WS_PBB + blockIdx.x] = w * wred[1][0];
  }
}

// ---------------- final: reduce stats, closed-form U-centered dots --------------------
__global__ __launch_bounds__(256) void final_kernel(const double* __restrict__ ws,
                                                    float* __restrict__ out)
{
  const int t = threadIdx.x;
  double sa = 0, sb = 0, uab = 0, uaa = 0, ubb = 0, ab = 0, aa = 0, bb = 0;
  for (int i = t; i < NPTS; i += 256) {
    double a = ws[WS_U_A + i], b = ws[WS_U_B + i];
    sa += a; sb += b; uab += a * b; uaa += a * a; ubb += b * b;
  }
  for (int i = t; i < NTILES; i += 256) {
    ab += ws[WS_PAB + i]; aa += ws[WS_PAA + i]; bb += ws[WS_PBB + i];
  }
  for (int off = 32; off; off >>= 1) {
    sa  += __shfl_down(sa, off);  sb  += __shfl_down(sb, off);
    uab += __shfl_down(uab, off); uaa += __shfl_down(uaa, off); ubb += __shfl_down(ubb, off);
    ab  += __shfl_down(ab, off);  aa  += __shfl_down(aa, off);  bb  += __shfl_down(bb, off);
  }
  __shared__ double red[4][8];
  int wave = t >> 6, lane = t & 63;
  if (lane == 0) {
    red[wave][0] = sa;  red[wave][1] = sb;  red[wave][2] = uab; red[wave][3] = uaa;
    red[wave][4] = ubb; red[wave][5] = ab;  red[wave][6] = aa;  red[wave][7] = bb;
  }
  __syncthreads();
  if (t == 0) {
    double v[8] = {0,0,0,0,0,0,0,0};
    for (int q = 0; q < 4; ++q) for (int z = 0; z < 8; ++z) v[z] += red[q][z];
    const double SA = v[0], SB = v[1], UAB = v[2], UAA = v[3], UBB = v[4];
    const double PAB = v[5], PAA = v[6], PBB = v[7];
    const double n = (double)NPTS, nm2 = n - 2.0;
    auto dotv = [&](double P, double U, double sx, double sy) {
      double tX = sx / ((n - 1.0) * nm2), tY = sy / ((n - 1.0) * nm2);
      double RX = sx / nm2, RY = sy / nm2;
      double su  = U / nm2;
      double srr = U / (nm2 * nm2);
      double full = P - 4.0 * su + tY * sx + tX * sy + 2.0 * n * srr + 2.0 * RX * RY
                  - 2.0 * n * tY * RX - 2.0 * n * tX * RY + n * n * tX * tY;
      double dg = n * tX * tY - 2.0 * tX * RY - 2.0 * tY * RX + 4.0 * srr;
      return full - dg;
    };
    const double denomc = n * (n - 3.0);
    double dab = dotv(PAB, UAB, SA, SB) / denomc;
    double daa = dotv(PAA, UAA, SA, SA) / denomc;
    double dbb = dotv(PBB, UBB, SB, SB) / denomc;
    double dn = sqrt(daa * dbb);
    if (dn < 1e-9) dn = 1e-9;
    out[0] = (float)(dab / dn);
  }
}

extern "C" void kernel_launch(void* const* d_in, const int* in_sizes, int n_in,
                              void* d_out, int out_size, void* d_ws, size_t ws_size,
                              hipStream_t stream) {
  const float* fa = (const float*)d_in[0];
  const float* fb = (const float*)d_in[1];
  double* ws = (double*)d_ws;

  hipMemsetAsync(d_ws, 0, WS_ZERO_DOUBLES * sizeof(double), stream);
  sq_kernel<<<dim3(NPTS / 4, 2), 256, 0, stream>>>(fa, fb, ws);
  gram_kernel<<<NTILES, 128, 0, stream>>>(fa, fb, ws);
  final_kernel<<<1, 256, 0, stream>>>(ws, (float*)d_out);
}

// Round 12
// 206.823 us; speedup vs baseline: 3.3798x; 2.5844x over previous
//
#include <hip/hip_runtime.h>
#include <hip/hip_fp16.h>
#include <math.h>

typedef float    f32x4 __attribute__((ext_vector_type(4)));
typedef _Float16 f16x4 __attribute__((ext_vector_type(4)));
typedef _Float16 f16x8 __attribute__((ext_vector_type(8)));
typedef unsigned short u16x4 __attribute__((ext_vector_type(4)));

#define NPTS 4096
#define DIM  512
#define NTB  64
#define NTILES (NTB*(NTB+1)/2)       // 2080 upper-tri tiles

// ws layout (doubles), then fp16 split arrays at 256 KiB
#define WS_U_A   0
#define WS_U_B   4096
#define WS_PAB   8192
#define WS_PAA   (8192 + NTILES)
#define WS_PBB   (8192 + 2*NTILES)
#define WS_SQA   (8192 + 3*NTILES)
#define WS_SQB   (WS_SQA + NPTS)
#define WS_ZERO_DOUBLES WS_SQA
#define WS_F16_BYTE_OFF 262144ull
#define HELEMS ((size_t)NPTS * DIM)   // 2M f16 per split array (4 MB)

__device__ __forceinline__ void tri_decode(int t, int& bi, int& bj) {
  int r = (int)((sqrt(8.0 * (double)t + 1.0) - 1.0) * 0.5);
  while ((r + 1) * (r + 2) / 2 <= t) ++r;
  while (r * (r + 1) / 2 > t) --r;
  bj = r; bi = t - r * (r + 1) / 2;   // bi <= bj
}

__device__ __forceinline__ void gload16h(const _Float16* g, _Float16* lds) {
  __builtin_amdgcn_global_load_lds(
      (const __attribute__((address_space(1))) void*)g,
      (__attribute__((address_space(3))) void*)lds, 16, 0, 0);
}

// ---------------- sq kernel: sq[i] = sum_k x[i][k]^2 (double) — unchanged ----------------
__global__ __launch_bounds__(256) void sq_kernel(const float* __restrict__ fa,
                                                 const float* __restrict__ fb,
                                                 double* __restrict__ ws) {
  int wave = threadIdx.x >> 6, lane = threadIdx.x & 63;
  int row = blockIdx.x * 4 + wave;
  const float* src = blockIdx.y ? fb : fa;
  double*      dst = blockIdx.y ? (ws + WS_SQB) : (ws + WS_SQA);
  const f32x4* p = (const f32x4*)(src + (size_t)row * DIM);
  double s = 0.0;
#pragma unroll
  for (int c = 0; c < DIM / 4 / 64; ++c) {
    f32x4 v = p[lane + c * 64];
    s += (double)v[0]*v[0] + (double)v[1]*v[1] + (double)v[2]*v[2] + (double)v[3]*v[3];
  }
  for (int off = 32; off; off >>= 1) s += __shfl_down(s, off);
  if (lane == 0) dst[row] = s;
}

// ---------------- split kernel: f32 -> (h0, h1*2048) fp16, MFMA-staging layout ----------------
// Layout per 64-row band: [chunk 16][sub 4][r16 16][phys-slot 8][4k] f16, where
// phys-slot = (k/4 within chunk) ^ (r16 & 7)  (bank-decorrelating XOR, granule 4k = 8B).
// Element index: ((band*16 + c)*4 + sub)*512 + r16*32 + phys*4 + j.
__global__ __launch_bounds__(256) void split_kernel(
    const float* __restrict__ fa, const float* __restrict__ fb,
    _Float16* __restrict__ ha0, _Float16* __restrict__ ha1,
    _Float16* __restrict__ hb0, _Float16* __restrict__ hb1)
{
  const int wave = threadIdx.x >> 6, lane = threadIdx.x & 63;
  const int row = blockIdx.x * 4 + wave;
  const float* src = blockIdx.y ? fb : fa;
  _Float16* o0 = blockIdx.y ? hb0 : ha0;
  _Float16* o1 = blockIdx.y ? hb1 : ha1;

  const int band = row >> 6, sub = (row >> 4) & 3, r16 = row & 15;
  const int c  = lane >> 2;            // chunk (8 k per lane -> within one chunk)
  const int s0 = (lane & 3) * 2;       // first logical slot of this lane's 8 k

  const f32x4* p = (const f32x4*)(src + (size_t)row * DIM + lane * 8);
  f32x4 v0 = p[0], v1 = p[1];

  f16x4 a0, a1, b0, b1;
#pragma unroll
  for (int u = 0; u < 4; ++u) {
    float x = v0[u];
    _Float16 h = (_Float16)x;                       // RNE
    a0[u] = h;
    a1[u] = (_Float16)((x - (float)h) * 2048.0f);   // scaled residual (no subnormals)
    float y = v1[u];
    _Float16 g = (_Float16)y;
    b0[u] = g;
    b1[u] = (_Float16)((y - (float)g) * 2048.0f);
  }
  const size_t base = ((size_t)(band * 16 + c) * 4 + sub) * 512 + (size_t)r16 * 32;
  const int ph0 = ( s0      ^ (r16 & 7)) * 4;
  const int ph1 = ((s0 + 1) ^ (r16 & 7)) * 4;
  *(f16x4*)(o0 + base + ph0) = a0;
  *(f16x4*)(o0 + base + ph1) = b0;
  *(f16x4*)(o1 + base + ph0) = a1;
  *(f16x4*)(o1 + base + ph1) = b1;
}

// ---------------- MFMA gram + fp16 distances + all statistics ----------------
// 128 threads = 2 waves: wave0 -> A, wave1 -> B. Per wave: 64x64 tile = 4x4 MFMA
// 16x16 tiles, K=512 in 16 chunks of 32. 2-split f16 Gram:
//   G = accM + accC/2048, accM = sum x0*y0, accC = sum (x0*y1s + x1s*y0)  [f32 MFMA accs]
// Distances: d2 = si + sj - 2*G (f64), d = fp16_rne((float)sqrt(d2)), diag forced 0
// (identical quantization to all passing rounds; G accuracy ~1e-5 keeps the
//  statistic within ~0.05 bf16 cells of the frozen pipeline).
__global__ void __launch_bounds__(128, 1)
gram_kernel(const _Float16* __restrict__ HA0, const _Float16* __restrict__ HA1,
            const _Float16* __restrict__ HB0, const _Float16* __restrict__ HB1,
            double* __restrict__ ws)
{
  const int raw = blockIdx.x;
  const int bid = (raw & 7) * 260 + (raw >> 3);   // bijective XCD swizzle (2080 = 8*260)
  int bi, bj; tri_decode(bid, bi, bj);
  const int i0 = bi * 64, j0 = bj * 64;
  const bool diag = (bi == bj);

  __shared__ _Float16 smem[32768];   // 64 KB: 2 dbuf x 2 waves x 4 panels x 2048 elems
  __shared__ double wred[2][2];

  const int t = threadIdx.x, wave = t >> 6, lane = t & 63;
  const int cq = lane & 15, rq = lane >> 4;

  const _Float16* S0 = wave ? HB0 : HA0;
  const _Float16* S1 = wave ? HB1 : HA1;

  f32x4 accM[4][4], accC[4][4];
#pragma unroll
  for (int a = 0; a < 4; ++a)
#pragma unroll
    for (int b = 0; b < 4; ++b) { accM[a][b] = (f32x4){0,0,0,0}; accC[a][b] = (f32x4){0,0,0,0}; }

  // ---- staging: 16 global_load_lds per wave per chunk (linear dest, 4 KB/panel) ----
#define STAGE(cc, buf) {                                                        \
    _Float16* W = smem + (buf) * 16384 + wave * 8192;                           \
    const size_t bI = ((size_t)(bi * 16 + (cc)) * 4) * 512 + lane * 8;          \
    const size_t bJ = ((size_t)(bj * 16 + (cc)) * 4) * 512 + lane * 8;          \
    _Pragma("unroll")                                                           \
    for (int sub = 0; sub < 4; ++sub) {                                         \
      gload16h(S0 + bI + sub * 512, W +        sub * 512);                      \
      gload16h(S1 + bI + sub * 512, W + 2048 + sub * 512);                      \
      gload16h(S0 + bJ + sub * 512, W + 4096 + sub * 512);                      \
      gload16h(S1 + bJ + sub * 512, W + 6144 + sub * 512);                      \
    } }

  STAGE(0, 0)
  __syncthreads();

#pragma unroll 1
  for (int c = 0; c < 16; ++c) {
    if (c < 15) STAGE(c + 1, (c + 1) & 1)
    const _Float16* P = smem + (c & 1) * 16384 + wave * 8192;

    f16x8 A0[4], A1[4], B0[4], B1[4];
#pragma unroll
    for (int ti = 0; ti < 4; ++ti) {
      const int o0 = ti * 512 + cq * 32 + (( rq      ^ (cq & 7)) << 2);
      const int o1 = ti * 512 + cq * 32 + (((rq + 4) ^ (cq & 7)) << 2);
      f16x4 l0, l1;
      l0 = *(const f16x4*)(P +        o0); l1 = *(const f16x4*)(P +        o1);
      A0[ti] = __builtin_shufflevector(l0, l1, 0,1,2,3,4,5,6,7);
      l0 = *(const f16x4*)(P + 2048 + o0); l1 = *(const f16x4*)(P + 2048 + o1);
      A1[ti] = __builtin_shufflevector(l0, l1, 0,1,2,3,4,5,6,7);
      l0 = *(const f16x4*)(P + 4096 + o0); l1 = *(const f16x4*)(P + 4096 + o1);
      B0[ti] = __builtin_shufflevector(l0, l1, 0,1,2,3,4,5,6,7);
      l0 = *(const f16x4*)(P + 6144 + o0); l1 = *(const f16x4*)(P + 6144 + o1);
      B1[ti] = __builtin_shufflevector(l0, l1, 0,1,2,3,4,5,6,7);
    }
#pragma unroll
    for (int ti = 0; ti < 4; ++ti)
#pragma unroll
      for (int tj = 0; tj < 4; ++tj) {
        accM[ti][tj] = __builtin_amdgcn_mfma_f32_16x16x32_f16(A0[ti], B0[tj], accM[ti][tj], 0, 0, 0);
        accC[ti][tj] = __builtin_amdgcn_mfma_f32_16x16x32_f16(A0[ti], B1[tj], accC[ti][tj], 0, 0, 0);
        accC[ti][tj] = __builtin_amdgcn_mfma_f32_16x16x32_f16(A1[ti], B0[tj], accC[ti][tj], 0, 0, 0);
      }
    __syncthreads();
  }

  // ---- epilogue: fp16 distances + stats. C/D layout (m89-verified):
  //      col = lane&15 (=cq), row = (lane>>4)*4 + reg (=rq*4+r) within each 16x16 tile.
  unsigned short* db = (unsigned short*)smem;   // 8 KB reuse for A/B fp16 exchange

  const double* sqx = ws + (wave ? WS_SQB : WS_SQA);
  double*       uxp = ws + (wave ? WS_U_B : WS_U_A);

  double si[16], sj[4];
#pragma unroll
  for (int ti = 0; ti < 4; ++ti)
#pragma unroll
    for (int r = 0; r < 4; ++r)
      si[ti * 4 + r] = sqx[i0 + ti * 16 + rq * 4 + r];
#pragma unroll
  for (int tj = 0; tj < 4; ++tj) sj[tj] = sqx[j0 + tj * 16 + cq];

  double rs[16], cs[4] = {0, 0, 0, 0}, self = 0.0;
#pragma unroll
  for (int z = 0; z < 16; ++z) rs[z] = 0.0;
  unsigned short pk[4][4][4];

#pragma unroll
  for (int ti = 0; ti < 4; ++ti)
#pragma unroll
    for (int tj = 0; tj < 4; ++tj)
#pragma unroll
      for (int r = 0; r < 4; ++r) {
        double G = (double)accM[ti][tj][r] + (double)accC[ti][tj][r] * (1.0 / 2048.0);
        double d2 = si[ti * 4 + r] + sj[tj] - 2.0 * G;
        unsigned short bits = 0;
        double dq = 0.0;
        if (d2 > 0.0) {
          float df = (float)sqrt(d2);
          __half h = __float2half(df);          // RNE — frozen quantization
          bits = __half_as_ushort(h);
          dq = (double)__half2float(h);
        }
        if (diag && (ti * 16 + rq * 4 + r == tj * 16 + cq)) { bits = 0; dq = 0.0; }
        pk[ti][tj][r] = bits;
        rs[ti * 4 + r] += dq;
        cs[tj] += dq;
        self += dq * dq;
      }

  if (wave == 1) {
#pragma unroll
    for (int ti = 0; ti < 4; ++ti)
#pragma unroll
      for (int tj = 0; tj < 4; ++tj) {
        u16x4 v = {pk[ti][tj][0], pk[ti][tj][1], pk[ti][tj][2], pk[ti][tj][3]};
        *(u16x4*)(db + lane * 64 + (ti * 4 + tj) * 4) = v;
      }
  }

  // row sums -> u[i0 + ti*16 + rq*4 + r]: reduce over cq (xor 1,2,4,8)
#pragma unroll
  for (int z = 0; z < 16; ++z) {
    double v = rs[z];
    v += __shfl_xor(v, 1); v += __shfl_xor(v, 2); v += __shfl_xor(v, 4); v += __shfl_xor(v, 8);
    if (cq == 0) atomicAdd(&uxp[i0 + (z >> 2) * 16 + rq * 4 + (z & 3)], v);
  }
  if (!diag) {  // col sums -> u[j0 + tj*16 + cq]: reduce over rq (xor 16,32)
#pragma unroll
    for (int tj = 0; tj < 4; ++tj) {
      double v = cs[tj];
      v += __shfl_xor(v, 16); v += __shfl_xor(v, 32);
      if (lane < 16) atomicAdd(&uxp[j0 + tj * 16 + cq], v);
    }
  }

  __syncthreads();   // db fully written

  double pab = 0.0;
  if (wave == 0) {
#pragma unroll
    for (int ti = 0; ti < 4; ++ti)
#pragma unroll
      for (int tj = 0; tj < 4; ++tj) {
        u16x4 vb = *(const u16x4*)(db + lane * 64 + (ti * 4 + tj) * 4);
#pragma unroll
        for (int r = 0; r < 4; ++r)
          pab += (double)__half2float(__ushort_as_half(pk[ti][tj][r]))
               * (double)__half2float(__ushort_as_half(vb[r]));
      }
  }

  for (int off = 32; off; off >>= 1) {
    pab  += __shfl_down(pab, off);
    self += __shfl_down(self, off);
  }
  if (lane == 0) {
    wred[wave][0] = (wave == 0) ? pab  : self;   // wave0: pab, wave1: pbb
    wred[wave][1] = (wave == 0) ? self : 0.0;    // wave0: paa
  }
  __syncthreads();
  if (t == 0) {
    double w = diag ? 1.0 : 2.0;
    ws[WS_PAB + bid] = w * wred[0][0];
    ws[WS_PAA + bid] = w * wred[0][1];
    ws[WS_PBB + bid] = w * wred[1][0];
  }
}

// ---------------- final: reduce stats, closed-form U-centered dots --------------------
__global__ __launch_bounds__(256) void final_kernel(const double* __restrict__ ws,
                                                    float* __restrict__ out)
{
  const int t = threadIdx.x;
  double sa = 0, sb = 0, uab = 0, uaa = 0, ubb = 0, ab = 0, aa = 0, bb = 0;
  for (int i = t; i < NPTS; i += 256) {
    double a = ws[WS_U_A + i], b = ws[WS_U_B + i];
    sa += a; sb += b; uab += a * b; uaa += a * a; ubb += b * b;
  }
  for (int i = t; i < NTILES; i += 256) {
    ab += ws[WS_PAB + i]; aa += ws[WS_PAA + i]; bb += ws[WS_PBB + i];
  }
  for (int off = 32; off; off >>= 1) {
    sa  += __shfl_down(sa, off);  sb  += __shfl_down(sb, off);
    uab += __shfl_down(uab, off); uaa += __shfl_down(uaa, off); ubb += __shfl_down(ubb, off);
    ab  += __shfl_down(ab, off);  aa  += __shfl_down(aa, off);  bb  += __shfl_down(bb, off);
  }
  __shared__ double red[4][8];
  int wave = t >> 6, lane = t & 63;
  if (lane == 0) {
    red[wave][0] = sa;  red[wave][1] = sb;  red[wave][2] = uab; red[wave][3] = uaa;
    red[wave][4] = ubb; red[wave][5] = ab;  red[wave][6] = aa;  red[wave][7] = bb;
  }
  __syncthreads();
  if (t == 0) {
    double v[8] = {0,0,0,0,0,0,0,0};
    for (int q = 0; q < 4; ++q) for (int z = 0; z < 8; ++z) v[z] += red[q][z];
    const double SA = v[0], SB = v[1], UAB = v[2], UAA = v[3], UBB = v[4];
    const double PAB = v[5], PAA = v[6], PBB = v[7];
    const double n = (double)NPTS, nm2 = n - 2.0;
    auto dotv = [&](double P, double U, double sx, double sy) {
      double tX = sx / ((n - 1.0) * nm2), tY = sy / ((n - 1.0) * nm2);
      double RX = sx / nm2, RY = sy / nm2;
      double su  = U / nm2;
      double srr = U / (nm2 * nm2);
      double full = P - 4.0 * su + tY * sx + tX * sy + 2.0 * n * srr + 2.0 * RX * RY
                  - 2.0 * n * tY * RX - 2.0 * n * tX * RY + n * n * tX * tY;
      double dg = n * tX * tY - 2.0 * tX * RY - 2.0 * tY * RX + 4.0 * srr;
      return full - dg;
    };
    const double denomc = n * (n - 3.0);
    double dab = dotv(PAB, UAB, SA, SB) / denomc;
    double daa = dotv(PAA, UAA, SA, SA) / denomc;
    double dbb = dotv(PBB, UBB, SB, SB) / denomc;
    double dn = sqrt(daa * dbb);
    if (dn < 1e-9) dn = 1e-9;
    out[0] = (float)(dab / dn);
  }
}

extern "C" void kernel_launch(void* const* d_in, const int* in_sizes, int n_in,
                              void* d_out, int out_size, void* d_ws, size_t ws_size,
                              hipStream_t stream) {
  const float* fa = (const float*)d_in[0];
  const float* fb = (const float*)d_in[1];
  double* ws = (double*)d_ws;

  _Float16* HA0 = (_Float16*)((char*)d_ws + WS_F16_BYTE_OFF);
  _Float16* HA1 = HA0 + HELEMS;
  _Float16* HB0 = HA1 + HELEMS;
  _Float16* HB1 = HB0 + HELEMS;

  hipMemsetAsync(d_ws, 0, WS_ZERO_DOUBLES * sizeof(double), stream);
  sq_kernel<<<dim3(NPTS / 4, 2), 256, 0, stream>>>(fa, fb, ws);
  split_kernel<<<dim3(NPTS / 4, 2), 256, 0, stream>>>(fa, fb, HA0, HA1, HB0, HB1);
  gram_kernel<<<NTILES, 128, 0, stream>>>(HA0, HA1, HB0, HB1, ws);
  final_kernel<<<1, 256, 0, stream>>>(ws, (float*)d_out);
}

// Round 13
// 167.762 us; speedup vs baseline: 4.1667x; 1.2328x over previous
//
#include <hip/hip_runtime.h>
#include <hip/hip_fp16.h>
#include <math.h>

typedef float    f32x4 __attribute__((ext_vector_type(4)));
typedef _Float16 f16x4 __attribute__((ext_vector_type(4)));
typedef _Float16 f16x8 __attribute__((ext_vector_type(8)));
typedef unsigned short u16x4 __attribute__((ext_vector_type(4)));

#define NPTS 4096
#define DIM  512
#define NTB  64
#define NTILES (NTB*(NTB+1)/2)       // 2080 upper-tri tiles

// ws layout (doubles), then fp16 split arrays at 256 KiB
#define WS_U_A   0
#define WS_U_B   4096
#define WS_PAB   8192
#define WS_PAA   (8192 + NTILES)
#define WS_PBB   (8192 + 2*NTILES)
#define WS_SQA   (8192 + 3*NTILES)
#define WS_SQB   (WS_SQA + NPTS)
#define WS_ZERO_DOUBLES WS_SQA
#define WS_F16_BYTE_OFF 262144ull
#define HELEMS ((size_t)NPTS * DIM)   // 2M f16 per split array (4 MB)

__device__ __forceinline__ void tri_decode(int t, int& bi, int& bj) {
  int r = (int)((sqrt(8.0 * (double)t + 1.0) - 1.0) * 0.5);
  while ((r + 1) * (r + 2) / 2 <= t) ++r;
  while (r * (r + 1) / 2 > t) --r;
  bj = r; bi = t - r * (r + 1) / 2;   // bi <= bj
}

__device__ __forceinline__ void gload16h(const _Float16* g, _Float16* lds) {
  __builtin_amdgcn_global_load_lds(
      (const __attribute__((address_space(1))) void*)g,
      (__attribute__((address_space(3))) void*)lds, 16, 0, 0);
}

// ---------------- split+sq kernel: f32 -> (h0, h1*2048) fp16 + row sum-sq (f64) ----------------
// Split layout per 64-row band: [chunk 16][sub 4][r16 16][phys-slot 8][4k] f16,
// phys-slot = (k/4 within chunk) ^ (r16 & 7). sq replicates the original
// sq_kernel read pattern + shuffle tree exactly (bit-identical sq values).
__global__ __launch_bounds__(256) void split_kernel(
    const float* __restrict__ fa, const float* __restrict__ fb,
    _Float16* __restrict__ ha0, _Float16* __restrict__ ha1,
    _Float16* __restrict__ hb0, _Float16* __restrict__ hb1,
    double* __restrict__ ws)
{
  const int wave = threadIdx.x >> 6, lane = threadIdx.x & 63;
  const int row = blockIdx.x * 4 + wave;
  const float* src = blockIdx.y ? fb : fa;
  _Float16* o0 = blockIdx.y ? hb0 : ha0;
  _Float16* o1 = blockIdx.y ? hb1 : ha1;
  double*  dst = blockIdx.y ? (ws + WS_SQB) : (ws + WS_SQA);

  // ---- sq: exact replica of the original sq_kernel (order-frozen) ----
  {
    const f32x4* p = (const f32x4*)(src + (size_t)row * DIM);
    double s = 0.0;
#pragma unroll
    for (int c = 0; c < DIM / 4 / 64; ++c) {
      f32x4 v = p[lane + c * 64];
      s += (double)v[0]*v[0] + (double)v[1]*v[1] + (double)v[2]*v[2] + (double)v[3]*v[3];
    }
    for (int off = 32; off; off >>= 1) s += __shfl_down(s, off);
    if (lane == 0) dst[row] = s;
  }

  // ---- split ----
  const int band = row >> 6, sub = (row >> 4) & 3, r16 = row & 15;
  const int c  = lane >> 2;
  const int s0 = (lane & 3) * 2;

  const f32x4* p = (const f32x4*)(src + (size_t)row * DIM + lane * 8);
  f32x4 v0 = p[0], v1 = p[1];

  f16x4 a0, a1, b0, b1;
#pragma unroll
  for (int u = 0; u < 4; ++u) {
    float x = v0[u];
    _Float16 h = (_Float16)x;                       // RNE
    a0[u] = h;
    a1[u] = (_Float16)((x - (float)h) * 2048.0f);   // scaled residual
    float y = v1[u];
    _Float16 g = (_Float16)y;
    b0[u] = g;
    b1[u] = (_Float16)((y - (float)g) * 2048.0f);
  }
  const size_t base = ((size_t)(band * 16 + c) * 4 + sub) * 512 + (size_t)r16 * 32;
  const int ph0 = ( s0      ^ (r16 & 7)) * 4;
  const int ph1 = ((s0 + 1) ^ (r16 & 7)) * 4;
  *(f16x4*)(o0 + base + ph0) = a0;
  *(f16x4*)(o0 + base + ph1) = b0;
  *(f16x4*)(o1 + base + ph0) = a1;
  *(f16x4*)(o1 + base + ph1) = b1;
}

// ---------------- MFMA gram + fp16 distances + all statistics ----------------
// 256 threads = 4 waves: wave = {mat = wave>>1 (0:A,1:B), half = wave&1}.
// Each wave computes ti in {half*2, half*2+1} x tj 0..3 (2x4 MFMA 16x16 tiles).
// Same LDS (64 KB) as round 12 -> 2 blocks/CU but 8 waves/CU (2/SIMD).
// NUMERICS FROZEN (round 12 bit-validated): G = accM + accC/2048 via
// mfma_f32_16x16x32_f16, 16 chunks ascending, per-tile MFMA order
// {A0B0->accM, A0B1->accC, A1B0->accC}; d2 = si+sj-2G (f64),
// d = fp16_rne((float)sqrt(d2)), diag forced 0.
__global__ void __launch_bounds__(256, 1)
gram_kernel(const _Float16* __restrict__ HA0, const _Float16* __restrict__ HA1,
            const _Float16* __restrict__ HB0, const _Float16* __restrict__ HB1,
            double* __restrict__ ws)
{
  const int raw = blockIdx.x;
  const int bid = (raw & 7) * 260 + (raw >> 3);   // bijective XCD swizzle (2080 = 8*260)
  int bi, bj; tri_decode(bid, bi, bj);
  const int i0 = bi * 64, j0 = bj * 64;
  const bool diag = (bi == bj);

  __shared__ _Float16 smem[32768];   // 64 KB: 2 dbuf x 2 mats x 4 panels x 2048 f16
  __shared__ double wred[4][2];

  const int t = threadIdx.x, wave = t >> 6, lane = t & 63;
  const int mat = wave >> 1, half = wave & 1;
  const int cq = lane & 15, rq = lane >> 4;

  const _Float16* S0 = mat ? HB0 : HA0;
  const _Float16* S1 = mat ? HB1 : HA1;

  f32x4 accM[2][4], accC[2][4];
#pragma unroll
  for (int a = 0; a < 2; ++a)
#pragma unroll
    for (int b = 0; b < 4; ++b) { accM[a][b] = (f32x4){0,0,0,0}; accC[a][b] = (f32x4){0,0,0,0}; }

  // staging role: half==0 stages this mat's I panels, half==1 the J panels
  const int sband = half ? bj : bi;

#define STAGE(cc, buf) {                                                        \
    _Float16* W = smem + (buf) * 16384 + mat * 8192 + half * 4096;              \
    const size_t bS = ((size_t)(sband * 16 + (cc)) * 4) * 512 + lane * 8;       \
    _Pragma("unroll")                                                           \
    for (int sub = 0; sub < 4; ++sub) {                                         \
      gload16h(S0 + bS + sub * 512, W +        sub * 512);                      \
      gload16h(S1 + bS + sub * 512, W + 2048 + sub * 512);                      \
    } }

  STAGE(0, 0)
  __syncthreads();

#pragma unroll 1
  for (int c = 0; c < 16; ++c) {
    if (c < 15) STAGE(c + 1, (c + 1) & 1)
    const _Float16* P = smem + (c & 1) * 16384 + mat * 8192;

    f16x8 A0[2], A1[2], B0[4], B1[4];
#pragma unroll
    for (int ta = 0; ta < 2; ++ta) {
      const int ti = half * 2 + ta;
      const int o0 = ti * 512 + cq * 32 + (( rq      ^ (cq & 7)) << 2);
      const int o1 = ti * 512 + cq * 32 + (((rq + 4) ^ (cq & 7)) << 2);
      f16x4 l0, l1;
      l0 = *(const f16x4*)(P +        o0); l1 = *(const f16x4*)(P +        o1);
      A0[ta] = __builtin_shufflevector(l0, l1, 0,1,2,3,4,5,6,7);
      l0 = *(const f16x4*)(P + 2048 + o0); l1 = *(const f16x4*)(P + 2048 + o1);
      A1[ta] = __builtin_shufflevector(l0, l1, 0,1,2,3,4,5,6,7);
    }
#pragma unroll
    for (int tj = 0; tj < 4; ++tj) {
      const int o0 = tj * 512 + cq * 32 + (( rq      ^ (cq & 7)) << 2);
      const int o1 = tj * 512 + cq * 32 + (((rq + 4) ^ (cq & 7)) << 2);
      f16x4 l0, l1;
      l0 = *(const f16x4*)(P + 4096 + o0); l1 = *(const f16x4*)(P + 4096 + o1);
      B0[tj] = __builtin_shufflevector(l0, l1, 0,1,2,3,4,5,6,7);
      l0 = *(const f16x4*)(P + 6144 + o0); l1 = *(const f16x4*)(P + 6144 + o1);
      B1[tj] = __builtin_shufflevector(l0, l1, 0,1,2,3,4,5,6,7);
    }
#pragma unroll
    for (int ta = 0; ta < 2; ++ta)
#pragma unroll
      for (int tj = 0; tj < 4; ++tj) {
        accM[ta][tj] = __builtin_amdgcn_mfma_f32_16x16x32_f16(A0[ta], B0[tj], accM[ta][tj], 0, 0, 0);
        accC[ta][tj] = __builtin_amdgcn_mfma_f32_16x16x32_f16(A0[ta], B1[tj], accC[ta][tj], 0, 0, 0);
        accC[ta][tj] = __builtin_amdgcn_mfma_f32_16x16x32_f16(A1[ta], B0[tj], accC[ta][tj], 0, 0, 0);
      }
    __syncthreads();
  }

  // ---- epilogue: fp16 distances + stats. C/D layout (m89): col=cq, row=rq*4+r.
  unsigned short* db = (unsigned short*)smem;   // reuse: 2 halves x 4 KB

  const double* sqx = ws + (mat ? WS_SQB : WS_SQA);
  double*       uxp = ws + (mat ? WS_U_B : WS_U_A);

  double si[8], sj[4];
#pragma unroll
  for (int ta = 0; ta < 2; ++ta)
#pragma unroll
    for (int r = 0; r < 4; ++r)
      si[ta * 4 + r] = sqx[i0 + (half * 2 + ta) * 16 + rq * 4 + r];
#pragma unroll
  for (int tj = 0; tj < 4; ++tj) sj[tj] = sqx[j0 + tj * 16 + cq];

  double rs[8], cs[4] = {0, 0, 0, 0}, self = 0.0;
#pragma unroll
  for (int z = 0; z < 8; ++z) rs[z] = 0.0;
  unsigned short pk[2][4][4];

#pragma unroll
  for (int ta = 0; ta < 2; ++ta)
#pragma unroll
    for (int tj = 0; tj < 4; ++tj)
#pragma unroll
      for (int r = 0; r < 4; ++r) {
        double G = (double)accM[ta][tj][r] + (double)accC[ta][tj][r] * (1.0 / 2048.0);
        double d2 = si[ta * 4 + r] + sj[tj] - 2.0 * G;
        unsigned short bits = 0;
        double dq = 0.0;
        if (d2 > 0.0) {
          float df = (float)sqrt(d2);
          __half h = __float2half(df);          // RNE -- frozen quantization
          bits = __half_as_ushort(h);
          dq = (double)__half2float(h);
        }
        if (diag && ((half * 2 + ta) * 16 + rq * 4 + r == tj * 16 + cq)) { bits = 0; dq = 0.0; }
        pk[ta][tj][r] = bits;
        rs[ta * 4 + r] += dq;
        cs[tj] += dq;
        self += dq * dq;
      }

  if (mat == 1) {
#pragma unroll
    for (int ta = 0; ta < 2; ++ta)
#pragma unroll
      for (int tj = 0; tj < 4; ++tj) {
        u16x4 v = {pk[ta][tj][0], pk[ta][tj][1], pk[ta][tj][2], pk[ta][tj][3]};
        *(u16x4*)(db + half * 2048 + lane * 32 + (ta * 4 + tj) * 4) = v;
      }
  }

  // row sums -> u[i0 + row]: reduce over cq (xor 1,2,4,8)
#pragma unroll
  for (int z = 0; z < 8; ++z) {
    double v = rs[z];
    v += __shfl_xor(v, 1); v += __shfl_xor(v, 2); v += __shfl_xor(v, 4); v += __shfl_xor(v, 8);
    if (cq == 0) atomicAdd(&uxp[i0 + (half * 2 + (z >> 2)) * 16 + rq * 4 + (z & 3)], v);
  }
  if (!diag) {  // col sums -> u[j0 + col]: reduce over rq (xor 16,32); both halves atomically add
#pragma unroll
    for (int tj = 0; tj < 4; ++tj) {
      double v = cs[tj];
      v += __shfl_xor(v, 16); v += __shfl_xor(v, 32);
      if (lane < 16) atomicAdd(&uxp[j0 + tj * 16 + cq], v);
    }
  }

  __syncthreads();   // db fully written

  double pab = 0.0;
  if (mat == 0) {
#pragma unroll
    for (int ta = 0; ta < 2; ++ta)
#pragma unroll
      for (int tj = 0; tj < 4; ++tj) {
        u16x4 vb = *(const u16x4*)(db + half * 2048 + lane * 32 + (ta * 4 + tj) * 4);
#pragma unroll
        for (int r = 0; r < 4; ++r)
          pab += (double)__half2float(__ushort_as_half(pk[ta][tj][r]))
               * (double)__half2float(__ushort_as_half(vb[r]));
      }
  }

  for (int off = 32; off; off >>= 1) {
    pab  += __shfl_down(pab, off);
    self += __shfl_down(self, off);
  }
  if (lane == 0) {
    wred[wave][0] = (mat == 0) ? pab  : self;   // A waves: pab-half, B waves: pbb-half
    wred[wave][1] = (mat == 0) ? self : 0.0;    // A waves: paa-half
  }
  __syncthreads();
  if (t == 0) {
    double w = diag ? 1.0 : 2.0;
    ws[WS_PAB + bid] = w * (wred[0][0] + wred[1][0]);
    ws[WS_PAA + bid] = w * (wred[0][1] + wred[1][1]);
    ws[WS_PBB + bid] = w * (wred[2][0] + wred[3][0]);
  }
}

// ---------------- final: reduce stats, closed-form U-centered dots --------------------
__global__ __launch_bounds__(256) void final_kernel(const double* __restrict__ ws,
                                                    float* __restrict__ out)
{
  const int t = threadIdx.x;
  double sa = 0, sb = 0, uab = 0, uaa = 0, ubb = 0, ab = 0, aa = 0, bb = 0;
  for (int i = t; i < NPTS; i += 256) {
    double a = ws[WS_U_A + i], b = ws[WS_U_B + i];
    sa += a; sb += b; uab += a * b; uaa += a * a; ubb += b * b;
  }
  for (int i = t; i < NTILES; i += 256) {
    ab += ws[WS_PAB + i]; aa += ws[WS_PAA + i]; bb += ws[WS_PBB + i];
  }
  for (int off = 32; off; off >>= 1) {
    sa  += __shfl_down(sa, off);  sb  += __shfl_down(sb, off);
    uab += __shfl_down(uab, off); uaa += __shfl_down(uaa, off); ubb += __shfl_down(ubb, off);
    ab  += __shfl_down(ab, off);  aa  += __shfl_down(aa, off);  bb  += __shfl_down(bb, off);
  }
  __shared__ double red[4][8];
  int wave = t >> 6, lane = t & 63;
  if (lane == 0) {
    red[wave][0] = sa;  red[wave][1] = sb;  red[wave][2] = uab; red[wave][3] = uaa;
    red[wave][4] = ubb; red[wave][5] = ab;  red[wave][6] = aa;  red[wave][7] = bb;
  }
  __syncthreads();
  if (t == 0) {
    double v[8] = {0,0,0,0,0,0,0,0};
    for (int q = 0; q < 4; ++q) for (int z = 0; z < 8; ++z) v[z] += red[q][z];
    const double SA = v[0], SB = v[1], UAB = v[2], UAA = v[3], UBB = v[4];
    const double PAB = v[5], PAA = v[6], PBB = v[7];
    const double n = (double)NPTS, nm2 = n - 2.0;
    auto dotv = [&](double P, double U, double sx, double sy) {
      double tX = sx / ((n - 1.0) * nm2), tY = sy / ((n - 1.0) * nm2);
      double RX = sx / nm2, RY = sy / nm2;
      double su  = U / nm2;
      double srr = U / (nm2 * nm2);
      double full = P - 4.0 * su + tY * sx + tX * sy + 2.0 * n * srr + 2.0 * RX * RY
                  - 2.0 * n * tY * RX - 2.0 * n * tX * RY + n * n * tX * tY;
      double dg = n * tX * tY - 2.0 * tX * RY - 2.0 * tY * RX + 4.0 * srr;
      return full - dg;
    };
    const double denomc = n * (n - 3.0);
    double dab = dotv(PAB, UAB, SA, SB) / denomc;
    double daa = dotv(PAA, UAA, SA, SA) / denomc;
    double dbb = dotv(PBB, UBB, SB, SB) / denomc;
    double dn = sqrt(daa * dbb);
    if (dn < 1e-9) dn = 1e-9;
    out[0] = (float)(dab / dn);
  }
}

extern "C" void kernel_launch(void* const* d_in, const int* in_sizes, int n_in,
                              void* d_out, int out_size, void* d_ws, size_t ws_size,
                              hipStream_t stream) {
  const float* fa = (const float*)d_in[0];
  const float* fb = (const float*)d_in[1];
  double* ws = (double*)d_ws;

  _Float16* HA0 = (_Float16*)((char*)d_ws + WS_F16_BYTE_OFF);
  _Float16* HA1 = HA0 + HELEMS;
  _Float16* HB0 = HA1 + HELEMS;
  _Float16* HB1 = HB0 + HELEMS;

  hipMemsetAsync(d_ws, 0, WS_ZERO_DOUBLES * sizeof(double), stream);
  split_kernel<<<dim3(NPTS / 4, 2), 256, 0, stream>>>(fa, fb, HA0, HA1, HB0, HB1, ws);
  gram_kernel<<<NTILES, 256, 0, stream>>>(HA0, HA1, HB0, HB1, ws);
  final_kernel<<<1, 256, 0, stream>>>(ws, (float*)d_out);
}

// Round 14
// 150.120 us; speedup vs baseline: 4.6564x; 1.1175x over previous
//
#include <hip/hip_runtime.h>
#include <hip/hip_fp16.h>
#include <math.h>

typedef float    f32x4 __attribute__((ext_vector_type(4)));
typedef _Float16 f16x8 __attribute__((ext_vector_type(8)));
typedef unsigned short u16x4 __attribute__((ext_vector_type(4)));

#define NPTS 4096
#define DIM  512
#define NTB  64
#define NTILES (NTB*(NTB+1)/2)       // 2080 upper-tri tiles

// ws layout (doubles), then fp16 split arrays at 256 KiB
#define WS_U_A   0
#define WS_U_B   4096
#define WS_PAB   8192
#define WS_PAA   (8192 + NTILES)
#define WS_PBB   (8192 + 2*NTILES)
#define WS_SQA   (8192 + 3*NTILES)
#define WS_SQB   (WS_SQA + NPTS)
#define WS_ZERO_DOUBLES WS_SQA
#define WS_F16_BYTE_OFF 262144ull
#define HELEMS ((size_t)NPTS * DIM)   // 2M f16 per split array (4 MB)

__device__ __forceinline__ void tri_decode(int t, int& bi, int& bj) {
  int r = (int)((sqrt(8.0 * (double)t + 1.0) - 1.0) * 0.5);
  while ((r + 1) * (r + 2) / 2 <= t) ++r;
  while (r * (r + 1) / 2 > t) --r;
  bj = r; bi = t - r * (r + 1) / 2;   // bi <= bj
}

__device__ __forceinline__ void gload16h(const _Float16* g, _Float16* lds) {
  __builtin_amdgcn_global_load_lds(
      (const __attribute__((address_space(1))) void*)g,
      (__attribute__((address_space(3))) void*)lds, 16, 0, 0);
}

// ---------------- split+sq kernel: f32 -> (h0, h1*2048) fp16 + row sum-sq (f64) ----------------
// Split layout per 64-row band: [chunk 16][sub 4][r16 16][phys-granule 4][8k] f16.
// Granule g holds k = g*8..g*8+7 (contiguous); physical slot = g ^ ((r16>>1)&3)
// (2-way bank aliasing on b128 reads = free). sq replicates the original
// sq_kernel read pattern + shuffle tree exactly (bit-identical sq values).
__global__ __launch_bounds__(256) void split_kernel(
    const float* __restrict__ fa, const float* __restrict__ fb,
    _Float16* __restrict__ ha0, _Float16* __restrict__ ha1,
    _Float16* __restrict__ hb0, _Float16* __restrict__ hb1,
    double* __restrict__ ws)
{
  const int wave = threadIdx.x >> 6, lane = threadIdx.x & 63;
  const int row = blockIdx.x * 4 + wave;
  const float* src = blockIdx.y ? fb : fa;
  _Float16* o0 = blockIdx.y ? hb0 : ha0;
  _Float16* o1 = blockIdx.y ? hb1 : ha1;
  double*  dst = blockIdx.y ? (ws + WS_SQB) : (ws + WS_SQA);

  // ---- sq: exact replica of the original sq_kernel (order-frozen) ----
  {
    const f32x4* p = (const f32x4*)(src + (size_t)row * DIM);
    double s = 0.0;
#pragma unroll
    for (int c = 0; c < DIM / 4 / 64; ++c) {
      f32x4 v = p[lane + c * 64];
      s += (double)v[0]*v[0] + (double)v[1]*v[1] + (double)v[2]*v[2] + (double)v[3]*v[3];
    }
    for (int off = 32; off; off >>= 1) s += __shfl_down(s, off);
    if (lane == 0) dst[row] = s;
  }

  // ---- split: lane covers k = lane*8 .. lane*8+7 (chunk = lane>>2, granule = lane&3) ----
  const int band = row >> 6, sub = (row >> 4) & 3, r16 = row & 15;
  const int c = lane >> 2, g = lane & 3;

  const f32x4* p = (const f32x4*)(src + (size_t)row * DIM + lane * 8);
  f32x4 v0 = p[0], v1 = p[1];

  f16x8 h0, h1;
#pragma unroll
  for (int u = 0; u < 4; ++u) {
    float x = v0[u];
    _Float16 h = (_Float16)x;                          // RNE
    h0[u] = h;
    h1[u] = (_Float16)((x - (float)h) * 2048.0f);      // scaled residual
    float y = v1[u];
    _Float16 hh = (_Float16)y;
    h0[u + 4] = hh;
    h1[u + 4] = (_Float16)((y - (float)hh) * 2048.0f);
  }
  const size_t base = ((size_t)(band * 16 + c) * 4 + sub) * 512 + (size_t)r16 * 32;
  const int gp = (g ^ ((r16 >> 1) & 3)) * 8;
  *(f16x8*)(o0 + base + gp) = h0;
  *(f16x8*)(o1 + base + gp) = h1;
}

// ---------------- MFMA gram + fp16 distances + all statistics ----------------
// 512 threads = 8 waves: mat = wave>>2 (0:A,1:B), q = wave&3 (row-quarter).
// Each wave: 1x4 MFMA 16x16 C-tiles (ti = q, tj 0..3), K=512 in 16 chunks of 32.
// 64 KB LDS (2 dbuf x 2 mats x {I0,I1,J0,J1}) -> 2 blocks/CU x 8 waves = 4 waves/SIMD.
// NUMERICS FROZEN (r12/r13 bit-validated): G = accM + accC/2048 via
// mfma_f32_16x16x32_f16, chunks ascending, per-tile order {A0B0->M, A0B1->C, A1B0->C};
// d2 = si+sj-2G (f64), d = fp16_rne((float)sqrt(d2)), diag forced 0.
__global__ void __launch_bounds__(512, 4)
gram_kernel(const _Float16* __restrict__ HA0, const _Float16* __restrict__ HA1,
            const _Float16* __restrict__ HB0, const _Float16* __restrict__ HB1,
            double* __restrict__ ws)
{
  const int raw = blockIdx.x;
  const int bid = (raw & 7) * 260 + (raw >> 3);   // bijective XCD swizzle (2080 = 8*260)
  int bi, bj; tri_decode(bid, bi, bj);
  const int i0 = bi * 64, j0 = bj * 64;
  const bool diag = (bi == bj);

  __shared__ _Float16 smem[32768];   // 64 KB
  __shared__ double wred[8][2];

  const int t = threadIdx.x, wave = t >> 6, lane = t & 63;
  const int mat = wave >> 2, q = wave & 3;
  const int cq = lane & 15, rq = lane >> 4;

  const _Float16* S0 = mat ? HB0 : HA0;
  const _Float16* S1 = mat ? HB1 : HA1;

  f32x4 accM[4], accC[4];
#pragma unroll
  for (int b = 0; b < 4; ++b) { accM[b] = (f32x4){0,0,0,0}; accC[b] = (f32x4){0,0,0,0}; }

  // staging: each wave stages sub q of its mat's I and J panels (4 gload_lds/chunk)
#define STAGE(cc, buf) {                                                        \
    _Float16* W = smem + (buf) * 16384 + mat * 8192 + q * 512;                  \
    const size_t bI = ((size_t)(bi * 16 + (cc)) * 4 + q) * 512 + lane * 8;      \
    const size_t bJ = ((size_t)(bj * 16 + (cc)) * 4 + q) * 512 + lane * 8;      \
    gload16h(S0 + bI, W);                                                       \
    gload16h(S1 + bI, W + 2048);                                                \
    gload16h(S0 + bJ, W + 4096);                                                \
    gload16h(S1 + bJ, W + 6144);                                                \
  }

  STAGE(0, 0)
  __syncthreads();

  const int fo = cq * 32 + ((rq ^ ((cq >> 1) & 3)) << 3);   // frag offset (de-swizzle)

#pragma unroll 1
  for (int c = 0; c < 16; ++c) {
    if (c < 15) STAGE(c + 1, (c + 1) & 1)
    const _Float16* P = smem + (c & 1) * 16384 + mat * 8192;

    f16x8 A0 = *(const f16x8*)(P +        q * 512 + fo);
    f16x8 A1 = *(const f16x8*)(P + 2048 + q * 512 + fo);
    f16x8 B0[4], B1[4];
#pragma unroll
    for (int tj = 0; tj < 4; ++tj) {
      B0[tj] = *(const f16x8*)(P + 4096 + tj * 512 + fo);
      B1[tj] = *(const f16x8*)(P + 6144 + tj * 512 + fo);
    }
#pragma unroll
    for (int tj = 0; tj < 4; ++tj) {
      accM[tj] = __builtin_amdgcn_mfma_f32_16x16x32_f16(A0, B0[tj], accM[tj], 0, 0, 0);
      accC[tj] = __builtin_amdgcn_mfma_f32_16x16x32_f16(A0, B1[tj], accC[tj], 0, 0, 0);
      accC[tj] = __builtin_amdgcn_mfma_f32_16x16x32_f16(A1, B0[tj], accC[tj], 0, 0, 0);
    }
    __syncthreads();
  }

  // ---- epilogue: fp16 distances + stats. C/D layout (m89): col=cq, row=rq*4+r (tile q,tj).
  unsigned short* db = (unsigned short*)smem;   // reuse: 4 quarters x 2 KB

  const double* sqx = ws + (mat ? WS_SQB : WS_SQA);
  double*       uxp = ws + (mat ? WS_U_B : WS_U_A);

  double si[4], sj[4];
#pragma unroll
  for (int r = 0; r < 4; ++r) si[r] = sqx[i0 + q * 16 + rq * 4 + r];
#pragma unroll
  for (int tj = 0; tj < 4; ++tj) sj[tj] = sqx[j0 + tj * 16 + cq];

  double rs[4] = {0,0,0,0}, cs[4] = {0,0,0,0}, self = 0.0;
  unsigned short pk[4][4];

#pragma unroll
  for (int tj = 0; tj < 4; ++tj)
#pragma unroll
    for (int r = 0; r < 4; ++r) {
      double G = (double)accM[tj][r] + (double)accC[tj][r] * (1.0 / 2048.0);
      double d2 = si[r] + sj[tj] - 2.0 * G;
      unsigned short bits = 0;
      double dq = 0.0;
      if (d2 > 0.0) {
        float df = (float)sqrt(d2);
        __half h = __float2half(df);          // RNE -- frozen quantization
        bits = __half_as_ushort(h);
        dq = (double)__half2float(h);
      }
      if (diag && (q * 16 + rq * 4 + r == tj * 16 + cq)) { bits = 0; dq = 0.0; }
      pk[tj][r] = bits;
      rs[r] += dq;
      cs[tj] += dq;
      self += dq * dq;
    }

  if (mat == 1) {
#pragma unroll
    for (int tj = 0; tj < 4; ++tj) {
      u16x4 v = {pk[tj][0], pk[tj][1], pk[tj][2], pk[tj][3]};
      *(u16x4*)(db + q * 1024 + lane * 16 + tj * 4) = v;
    }
  }

  // row sums -> u[i0 + q*16 + rq*4 + r]: reduce over cq (xor 1,2,4,8)
#pragma unroll
  for (int z = 0; z < 4; ++z) {
    double v = rs[z];
    v += __shfl_xor(v, 1); v += __shfl_xor(v, 2); v += __shfl_xor(v, 4); v += __shfl_xor(v, 8);
    if (cq == 0) atomicAdd(&uxp[i0 + q * 16 + rq * 4 + z], v);
  }
  if (!diag) {  // col sums -> u[j0 + tj*16 + cq]: reduce over rq (xor 16,32); 4 stripes add
#pragma unroll
    for (int tj = 0; tj < 4; ++tj) {
      double v = cs[tj];
      v += __shfl_xor(v, 16); v += __shfl_xor(v, 32);
      if (lane < 16) atomicAdd(&uxp[j0 + tj * 16 + cq], v);
    }
  }

  __syncthreads();   // db fully written

  double pab = 0.0;
  if (mat == 0) {
#pragma unroll
    for (int tj = 0; tj < 4; ++tj) {
      u16x4 vb = *(const u16x4*)(db + q * 1024 + lane * 16 + tj * 4);
#pragma unroll
      for (int r = 0; r < 4; ++r)
        pab += (double)__half2float(__ushort_as_half(pk[tj][r]))
             * (double)__half2float(__ushort_as_half(vb[r]));
    }
  }

  for (int off = 32; off; off >>= 1) {
    pab  += __shfl_down(pab, off);
    self += __shfl_down(self, off);
  }
  if (lane == 0) {
    wred[wave][0] = (mat == 0) ? pab  : self;   // A waves: pab_q, B waves: pbb_q
    wred[wave][1] = (mat == 0) ? self : 0.0;    // A waves: paa_q
  }
  __syncthreads();
  if (t == 0) {
    double w = diag ? 1.0 : 2.0;
    double s0 = 0, s1 = 0, s2 = 0;
    for (int z = 0; z < 4; ++z) { s0 += wred[z][0]; s1 += wred[z][1]; s2 += wred[4 + z][0]; }
    ws[WS_PAB + bid] = w * s0;
    ws[WS_PAA + bid] = w * s1;
    ws[WS_PBB + bid] = w * s2;
  }
}

// ---------------- final: reduce stats, closed-form U-centered dots --------------------
__global__ __launch_bounds__(256) void final_kernel(const double* __restrict__ ws,
                                                    float* __restrict__ out)
{
  const int t = threadIdx.x;
  double sa = 0, sb = 0, uab = 0, uaa = 0, ubb = 0, ab = 0, aa = 0, bb = 0;
  for (int i = t; i < NPTS; i += 256) {
    double a = ws[WS_U_A + i], b = ws[WS_U_B + i];
    sa += a; sb += b; uab += a * b; uaa += a * a; ubb += b * b;
  }
  for (int i = t; i < NTILES; i += 256) {
    ab += ws[WS_PAB + i]; aa += ws[WS_PAA + i]; bb += ws[WS_PBB + i];
  }
  for (int off = 32; off; off >>= 1) {
    sa  += __shfl_down(sa, off);  sb  += __shfl_down(sb, off);
    uab += __shfl_down(uab, off); uaa += __shfl_down(uaa, off); ubb += __shfl_down(ubb, off);
    ab  += __shfl_down(ab, off);  aa  += __shfl_down(aa, off);  bb  += __shfl_down(bb, off);
  }
  __shared__ double red[4][8];
  int wave = t >> 6, lane = t & 63;
  if (lane == 0) {
    red[wave][0] = sa;  red[wave][1] = sb;  red[wave][2] = uab; red[wave][3] = uaa;
    red[wave][4] = ubb; red[wave][5] = ab;  red[wave][6] = aa;  red[wave][7] = bb;
  }
  __syncthreads();
  if (t == 0) {
    double v[8] = {0,0,0,0,0,0,0,0};
    for (int qq = 0; qq < 4; ++qq) for (int z = 0; z < 8; ++z) v[z] += red[qq][z];
    const double SA = v[0], SB = v[1], UAB = v[2], UAA = v[3], UBB = v[4];
    const double PAB = v[5], PAA = v[6], PBB = v[7];
    const double n = (double)NPTS, nm2 = n - 2.0;
    auto dotv = [&](double P, double U, double sx, double sy) {
      double tX = sx / ((n - 1.0) * nm2), tY = sy / ((n - 1.0) * nm2);
      double RX = sx / nm2, RY = sy / nm2;
      double su  = U / nm2;
      double srr = U / (nm2 * nm2);
      double full = P - 4.0 * su + tY * sx + tX * sy + 2.0 * n * srr + 2.0 * RX * RY
                  - 2.0 * n * tY * RX - 2.0 * n * tX * RY + n * n * tX * tY;
      double dg = n * tX * tY - 2.0 * tX * RY - 2.0 * tY * RX + 4.0 * srr;
      return full - dg;
    };
    const double denomc = n * (n - 3.0);
    double dab = dotv(PAB, UAB, SA, SB) / denomc;
    double daa = dotv(PAA, UAA, SA, SA) / denomc;
    double dbb = dotv(PBB, UBB, SB, SB) / denomc;
    double dn = sqrt(daa * dbb);
    if (dn < 1e-9) dn = 1e-9;
    out[0] = (float)(dab / dn);
  }
}

extern "C" void kernel_launch(void* const* d_in, const int* in_sizes, int n_in,
                              void* d_out, int out_size, void* d_ws, size_t ws_size,
                              hipStream_t stream) {
  const float* fa = (const float*)d_in[0];
  const float* fb = (const float*)d_in[1];
  double* ws = (double*)d_ws;

  _Float16* HA0 = (_Float16*)((char*)d_ws + WS_F16_BYTE_OFF);
  _Float16* HA1 = HA0 + HELEMS;
  _Float16* HB0 = HA1 + HELEMS;
  _Float16* HB1 = HB0 + HELEMS;

  hipMemsetAsync(d_ws, 0, WS_ZERO_DOUBLES * sizeof(double), stream);
  split_kernel<<<dim3(NPTS / 4, 2), 256, 0, stream>>>(fa, fb, HA0, HA1, HB0, HB1, ws);
  gram_kernel<<<NTILES, 512, 0, stream>>>(HA0, HA1, HB0, HB1, ws);
  final_kernel<<<1, 256, 0, stream>>>(ws, (float*)d_out);
}

// Round 15
// 138.136 us; speedup vs baseline: 5.0604x; 1.0867x over previous
//
#include <hip/hip_runtime.h>
#include <hip/hip_fp16.h>
#include <math.h>

typedef float    f32x4 __attribute__((ext_vector_type(4)));
typedef _Float16 f16x8 __attribute__((ext_vector_type(8)));
typedef unsigned short u16x4 __attribute__((ext_vector_type(4)));

#define NPTS 4096
#define DIM  512
#define NTB  64
#define NTILES (NTB*(NTB+1)/2)       // 2080 upper-tri tiles

// ws layout (doubles), then fp16 split arrays at 256 KiB
#define WS_U_A   0
#define WS_U_B   4096
#define WS_PAB   8192
#define WS_PAA   (8192 + NTILES)
#define WS_PBB   (8192 + 2*NTILES)
#define WS_SQA   (8192 + 3*NTILES)
#define WS_SQB   (WS_SQA + NPTS)
#define WS_ZERO_DOUBLES WS_SQA
#define WS_F16_BYTE_OFF 262144ull
#define HELEMS ((size_t)NPTS * DIM)   // 2M f16 per split array (4 MB)

__device__ __forceinline__ void gload16h(const _Float16* g, _Float16* lds) {
  __builtin_amdgcn_global_load_lds(
      (const __attribute__((address_space(1))) void*)g,
      (__attribute__((address_space(3))) void*)lds, 16, 0, 0);
}

// ---- supertile tile mapping: 8x8-tile supertiles, diag supers first, then
// strict-upper supers; global order g chopped into 8 contiguous 260-tile
// ranges (one per XCD) via the round-robin dispatch swizzle. Bijection on
// [0,2080): 8 diag supers x 36 + 28 off-diag supers x 64 = 288 + 1792 = 2080.
__device__ __forceinline__ void map_tile(int raw, int& bi, int& bj) {
  const int g = (raw & 7) * 260 + (raw >> 3);
  if (g < 288) {
    const int s = g / 36, r = g % 36;        // diag supertile s, tri pair r (8x8)
    int rj = (int)((sqrtf(8.f * r + 1.f) - 1.f) * 0.5f);
    while ((rj + 1) * (rj + 2) / 2 <= r) ++rj;
    while (rj * (rj + 1) / 2 > r) --rj;
    const int ri = r - rj * (rj + 1) / 2;    // ri <= rj
    bi = s * 8 + ri; bj = s * 8 + rj;
  } else {
    const int e = g - 288;
    const int s = e / 64, r = e % 64;        // off-diag supertile s
    int SBJ = 1;                             // decode strict-upper pair (SBI < SBJ)
    while (SBJ * (SBJ + 1) / 2 <= s) ++SBJ;
    const int SBI = s - SBJ * (SBJ - 1) / 2;
    bi = SBI * 8 + (r >> 3); bj = SBJ * 8 + (r & 7);
  }
}

// ---------------- split+sq kernel: f32 -> (h0, h1*2048) fp16 + row sum-sq (f64) ----------------
// Split layout per 64-row band: [chunk 16][sub 4][r16 16][phys-granule 4][8k] f16.
// Granule g holds k = g*8..g*8+7 (contiguous); physical slot = g ^ ((r16>>1)&3).
// sq replicates the original sq_kernel read pattern + shuffle tree exactly.
__global__ __launch_bounds__(256) void split_kernel(
    const float* __restrict__ fa, const float* __restrict__ fb,
    _Float16* __restrict__ ha0, _Float16* __restrict__ ha1,
    _Float16* __restrict__ hb0, _Float16* __restrict__ hb1,
    double* __restrict__ ws)
{
  const int wave = threadIdx.x >> 6, lane = threadIdx.x & 63;
  const int row = blockIdx.x * 4 + wave;
  const float* src = blockIdx.y ? fb : fa;
  _Float16* o0 = blockIdx.y ? hb0 : ha0;
  _Float16* o1 = blockIdx.y ? hb1 : ha1;
  double*  dst = blockIdx.y ? (ws + WS_SQB) : (ws + WS_SQA);

  // ---- sq: exact replica of the original sq_kernel (order-frozen) ----
  {
    const f32x4* p = (const f32x4*)(src + (size_t)row * DIM);
    double s = 0.0;
#pragma unroll
    for (int c = 0; c < DIM / 4 / 64; ++c) {
      f32x4 v = p[lane + c * 64];
      s += (double)v[0]*v[0] + (double)v[1]*v[1] + (double)v[2]*v[2] + (double)v[3]*v[3];
    }
    for (int off = 32; off; off >>= 1) s += __shfl_down(s, off);
    if (lane == 0) dst[row] = s;
  }

  // ---- split: lane covers k = lane*8 .. lane*8+7 (chunk = lane>>2, granule = lane&3) ----
  const int band = row >> 6, sub = (row >> 4) & 3, r16 = row & 15;
  const int c = lane >> 2, g = lane & 3;

  const f32x4* p = (const f32x4*)(src + (size_t)row * DIM + lane * 8);
  f32x4 v0 = p[0], v1 = p[1];

  f16x8 h0, h1;
#pragma unroll
  for (int u = 0; u < 4; ++u) {
    float x = v0[u];
    _Float16 h = (_Float16)x;                          // RNE
    h0[u] = h;
    h1[u] = (_Float16)((x - (float)h) * 2048.0f);      // scaled residual
    float y = v1[u];
    _Float16 hh = (_Float16)y;
    h0[u + 4] = hh;
    h1[u + 4] = (_Float16)((y - (float)hh) * 2048.0f);
  }
  const size_t base = ((size_t)(band * 16 + c) * 4 + sub) * 512 + (size_t)r16 * 32;
  const int gp = (g ^ ((r16 >> 1) & 3)) * 8;
  *(f16x8*)(o0 + base + gp) = h0;
  *(f16x8*)(o1 + base + gp) = h1;
}

// ---------------- MFMA gram + fp16 distances + all statistics ----------------
// 512 threads = 8 waves: mat = wave>>2 (0:A,1:B), q = wave&3 (row-quarter).
// Each wave: 1x4 MFMA 16x16 C-tiles (ti = q, tj 0..3), K=512 in 16 chunks of 32.
// 64 KB LDS -> 2 blocks/CU x 8 waves = 4 waves/SIMD. Supertile bid mapping for
// L2 locality (pure schedule change; in-block computation identical to r14).
// NUMERICS FROZEN (r12-r14 bit-validated): G = accM + accC/2048 via
// mfma_f32_16x16x32_f16, chunks ascending, per-tile order {A0B0->M, A0B1->C, A1B0->C};
// d2 = si+sj-2G (f64), d = fp16_rne((float)sqrt(d2)), diag forced 0.
__global__ void __launch_bounds__(512, 4)
gram_kernel(const _Float16* __restrict__ HA0, const _Float16* __restrict__ HA1,
            const _Float16* __restrict__ HB0, const _Float16* __restrict__ HB1,
            double* __restrict__ ws)
{
  int bi, bj; map_tile(blockIdx.x, bi, bj);
  const int i0 = bi * 64, j0 = bj * 64;
  const bool diag = (bi == bj);

  __shared__ _Float16 smem[32768];   // 64 KB
  __shared__ double wred[8][2];

  const int t = threadIdx.x, wave = t >> 6, lane = t & 63;
  const int mat = wave >> 2, q = wave & 3;
  const int cq = lane & 15, rq = lane >> 4;

  const _Float16* S0 = mat ? HB0 : HA0;
  const _Float16* S1 = mat ? HB1 : HA1;

  f32x4 accM[4], accC[4];
#pragma unroll
  for (int b = 0; b < 4; ++b) { accM[b] = (f32x4){0,0,0,0}; accC[b] = (f32x4){0,0,0,0}; }

  // staging: each wave stages sub q of its mat's I and J panels (4 gload_lds/chunk)
#define STAGE(cc, buf) {                                                        \
    _Float16* W = smem + (buf) * 16384 + mat * 8192 + q * 512;                  \
    const size_t bI = ((size_t)(bi * 16 + (cc)) * 4 + q) * 512 + lane * 8;      \
    const size_t bJ = ((size_t)(bj * 16 + (cc)) * 4 + q) * 512 + lane * 8;      \
    gload16h(S0 + bI, W);                                                       \
    gload16h(S1 + bI, W + 2048);                                                \
    gload16h(S0 + bJ, W + 4096);                                                \
    gload16h(S1 + bJ, W + 6144);                                                \
  }

  STAGE(0, 0)
  __syncthreads();

  const int fo = cq * 32 + ((rq ^ ((cq >> 1) & 3)) << 3);   // frag offset (de-swizzle)

#pragma unroll 1
  for (int c = 0; c < 16; ++c) {
    if (c < 15) STAGE(c + 1, (c + 1) & 1)
    const _Float16* P = smem + (c & 1) * 16384 + mat * 8192;

    f16x8 A0 = *(const f16x8*)(P +        q * 512 + fo);
    f16x8 A1 = *(const f16x8*)(P + 2048 + q * 512 + fo);
    f16x8 B0[4], B1[4];
#pragma unroll
    for (int tj = 0; tj < 4; ++tj) {
      B0[tj] = *(const f16x8*)(P + 4096 + tj * 512 + fo);
      B1[tj] = *(const f16x8*)(P + 6144 + tj * 512 + fo);
    }
#pragma unroll
    for (int tj = 0; tj < 4; ++tj) {
      accM[tj] = __builtin_amdgcn_mfma_f32_16x16x32_f16(A0, B0[tj], accM[tj], 0, 0, 0);
      accC[tj] = __builtin_amdgcn_mfma_f32_16x16x32_f16(A0, B1[tj], accC[tj], 0, 0, 0);
      accC[tj] = __builtin_amdgcn_mfma_f32_16x16x32_f16(A1, B0[tj], accC[tj], 0, 0, 0);
    }
    __syncthreads();
  }

  // ---- epilogue: fp16 distances + stats. C/D layout (m89): col=cq, row=rq*4+r (tile q,tj).
  unsigned short* db = (unsigned short*)smem;   // reuse: 4 quarters x 2 KB

  const double* sqx = ws + (mat ? WS_SQB : WS_SQA);
  double*       uxp = ws + (mat ? WS_U_B : WS_U_A);

  double si[4], sj[4];
#pragma unroll
  for (int r = 0; r < 4; ++r) si[r] = sqx[i0 + q * 16 + rq * 4 + r];
#pragma unroll
  for (int tj = 0; tj < 4; ++tj) sj[tj] = sqx[j0 + tj * 16 + cq];

  double rs[4] = {0,0,0,0}, cs[4] = {0,0,0,0}, self = 0.0;
  unsigned short pk[4][4];

#pragma unroll
  for (int tj = 0; tj < 4; ++tj)
#pragma unroll
    for (int r = 0; r < 4; ++r) {
      double G = (double)accM[tj][r] + (double)accC[tj][r] * (1.0 / 2048.0);
      double d2 = si[r] + sj[tj] - 2.0 * G;
      unsigned short bits = 0;
      double dq = 0.0;
      if (d2 > 0.0) {
        float df = (float)sqrt(d2);
        __half h = __float2half(df);          // RNE -- frozen quantization
        bits = __half_as_ushort(h);
        dq = (double)__half2float(h);
      }
      if (diag && (q * 16 + rq * 4 + r == tj * 16 + cq)) { bits = 0; dq = 0.0; }
      pk[tj][r] = bits;
      rs[r] += dq;
      cs[tj] += dq;
      self += dq * dq;
    }

  if (mat == 1) {
#pragma unroll
    for (int tj = 0; tj < 4; ++tj) {
      u16x4 v = {pk[tj][0], pk[tj][1], pk[tj][2], pk[tj][3]};
      *(u16x4*)(db + q * 1024 + lane * 16 + tj * 4) = v;
    }
  }

  // row sums -> u[i0 + q*16 + rq*4 + r]: reduce over cq (xor 1,2,4,8)
#pragma unroll
  for (int z = 0; z < 4; ++z) {
    double v = rs[z];
    v += __shfl_xor(v, 1); v += __shfl_xor(v, 2); v += __shfl_xor(v, 4); v += __shfl_xor(v, 8);
    if (cq == 0) atomicAdd(&uxp[i0 + q * 16 + rq * 4 + z], v);
  }
  if (!diag) {  // col sums -> u[j0 + tj*16 + cq]: reduce over rq (xor 16,32); 4 stripes add
#pragma unroll
    for (int tj = 0; tj < 4; ++tj) {
      double v = cs[tj];
      v += __shfl_xor(v, 16); v += __shfl_xor(v, 32);
      if (lane < 16) atomicAdd(&uxp[j0 + tj * 16 + cq], v);
    }
  }

  __syncthreads();   // db fully written

  double pab = 0.0;
  if (mat == 0) {
#pragma unroll
    for (int tj = 0; tj < 4; ++tj) {
      u16x4 vb = *(const u16x4*)(db + q * 1024 + lane * 16 + tj * 4);
#pragma unroll
      for (int r = 0; r < 4; ++r)
        pab += (double)__half2float(__ushort_as_half(pk[tj][r]))
             * (double)__half2float(__ushort_as_half(vb[r]));
    }
  }

  for (int off = 32; off; off >>= 1) {
    pab  += __shfl_down(pab, off);
    self += __shfl_down(self, off);
  }
  if (lane == 0) {
    wred[wave][0] = (mat == 0) ? pab  : self;   // A waves: pab_q, B waves: pbb_q
    wred[wave][1] = (mat == 0) ? self : 0.0;    // A waves: paa_q
  }
  __syncthreads();
  if (t == 0) {
    double w = diag ? 1.0 : 2.0;
    double s0 = 0, s1 = 0, s2 = 0;
    for (int z = 0; z < 4; ++z) { s0 += wred[z][0]; s1 += wred[z][1]; s2 += wred[4 + z][0]; }
    ws[WS_PAB + blockIdx.x] = w * s0;
    ws[WS_PAA + blockIdx.x] = w * s1;
    ws[WS_PBB + blockIdx.x] = w * s2;
  }
}

// ---------------- final: reduce stats, closed-form U-centered dots --------------------
__global__ __launch_bounds__(256) void final_kernel(const double* __restrict__ ws,
                                                    float* __restrict__ out)
{
  const int t = threadIdx.x;
  double sa = 0, sb = 0, uab = 0, uaa = 0, ubb = 0, ab = 0, aa = 0, bb = 0;
  for (int i = t; i < NPTS; i += 256) {
    double a = ws[WS_U_A + i], b = ws[WS_U_B + i];
    sa += a; sb += b; uab += a * b; uaa += a * a; ubb += b * b;
  }
  for (int i = t; i < NTILES; i += 256) {
    ab += ws[WS_PAB + i]; aa += ws[WS_PAA + i]; bb += ws[WS_PBB + i];
  }
  for (int off = 32; off; off >>= 1) {
    sa  += __shfl_down(sa, off);  sb  += __shfl_down(sb, off);
    uab += __shfl_down(uab, off); uaa += __shfl_down(uaa, off); ubb += __shfl_down(ubb, off);
    ab  += __shfl_down(ab, off);  aa  += __shfl_down(aa, off);  bb  += __shfl_down(bb, off);
  }
  __shared__ double red[4][8];
  int wave = t >> 6, lane = t & 63;
  if (lane == 0) {
    red[wave][0] = sa;  red[wave][1] = sb;  red[wave][2] = uab; red[wave][3] = uaa;
    red[wave][4] = ubb; red[wave][5] = ab;  red[wave][6] = aa;  red[wave][7] = bb;
  }
  __syncthreads();
  if (t == 0) {
    double v[8] = {0,0,0,0,0,0,0,0};
    for (int qq = 0; qq < 4; ++qq) for (int z = 0; z < 8; ++z) v[z] += red[qq][z];
    const double SA = v[0], SB = v[1], UAB = v[2], UAA = v[3], UBB = v[4];
    const double PAB = v[5], PAA = v[6], PBB = v[7];
    const double n = (double)NPTS, nm2 = n - 2.0;
    auto dotv = [&](double P, double U, double sx, double sy) {
      double tX = sx / ((n - 1.0) * nm2), tY = sy / ((n - 1.0) * nm2);
      double RX = sx / nm2, RY = sy / nm2;
      double su  = U / nm2;
      double srr = U / (nm2 * nm2);
      double full = P - 4.0 * su + tY * sx + tX * sy + 2.0 * n * srr + 2.0 * RX * RY
                  - 2.0 * n * tY * RX - 2.0 * n * tX * RY + n * n * tX * tY;
      double dg = n * tX * tY - 2.0 * tX * RY - 2.0 * tY * RX + 4.0 * srr;
      return full - dg;
    };
    const double denomc = n * (n - 3.0);
    double dab = dotv(PAB, UAB, SA, SB) / denomc;
    double daa = dotv(PAA, UAA, SA, SA) / denomc;
    double dbb = dotv(PBB, UBB, SB, SB) / denomc;
    double dn = sqrt(daa * dbb);
    if (dn < 1e-9) dn = 1e-9;
    out[0] = (float)(dab / dn);
  }
}

extern "C" void kernel_launch(void* const* d_in, const int* in_sizes, int n_in,
                              void* d_out, int out_size, void* d_ws, size_t ws_size,
                              hipStream_t stream) {
  const float* fa = (const float*)d_in[0];
  const float* fb = (const float*)d_in[1];
  double* ws = (double*)d_ws;

  _Float16* HA0 = (_Float16*)((char*)d_ws + WS_F16_BYTE_OFF);
  _Float16* HA1 = HA0 + HELEMS;
  _Float16* HB0 = HA1 + HELEMS;
  _Float16* HB1 = HB0 + HELEMS;

  hipMemsetAsync(d_ws, 0, WS_ZERO_DOUBLES * sizeof(double), stream);
  split_kernel<<<dim3(NPTS / 4, 2), 256, 0, stream>>>(fa, fb, HA0, HA1, HB0, HB1, ws);
  gram_kernel<<<NTILES, 512, 0, stream>>>(HA0, HA1, HB0, HB1, ws);
  final_kernel<<<1, 256, 0, stream>>>(ws, (float*)d_out);
}

// Round 16
// 125.528 us; speedup vs baseline: 5.5686x; 1.1004x over previous
//
#include <hip/hip_runtime.h>
#include <hip/hip_fp16.h>
#include <math.h>

typedef float    f32x4 __attribute__((ext_vector_type(4)));
typedef _Float16 f16x8 __attribute__((ext_vector_type(8)));
typedef unsigned short u16x4 __attribute__((ext_vector_type(4)));

#define NPTS 4096
#define DIM  512
#define NTB  64
#define NTILES (NTB*(NTB+1)/2)       // 2080 upper-tri tiles

// ws layout (doubles), then fp16 split arrays at 256 KiB
#define WS_U_A   0
#define WS_U_B   4096
#define WS_PAB   8192
#define WS_PAA   (8192 + NTILES)
#define WS_PBB   (8192 + 2*NTILES)
#define WS_SQA   (8192 + 3*NTILES)
#define WS_SQB   (WS_SQA + NPTS)
#define WS_ZERO_DOUBLES WS_SQA
#define WS_F16_BYTE_OFF 262144ull
#define HELEMS ((size_t)NPTS * DIM)   // 2M f16 per split array (4 MB)

// ---- supertile tile mapping (r15-validated): 8x8-tile supertiles, diag supers
// first, then strict-upper supers; 8 contiguous 260-tile ranges via XCD swizzle.
__device__ __forceinline__ void map_tile(int raw, int& bi, int& bj) {
  const int g = (raw & 7) * 260 + (raw >> 3);
  if (g < 288) {
    const int s = g / 36, r = g % 36;
    int rj = (int)((sqrtf(8.f * r + 1.f) - 1.f) * 0.5f);
    while ((rj + 1) * (rj + 2) / 2 <= r) ++rj;
    while (rj * (rj + 1) / 2 > r) --rj;
    const int ri = r - rj * (rj + 1) / 2;
    bi = s * 8 + ri; bj = s * 8 + rj;
  } else {
    const int e = g - 288;
    const int s = e / 64, r = e % 64;
    int SBJ = 1;
    while (SBJ * (SBJ + 1) / 2 <= s) ++SBJ;
    const int SBI = s - SBJ * (SBJ - 1) / 2;
    bi = SBI * 8 + (r >> 3); bj = SBJ * 8 + (r & 7);
  }
}

// ---------------- split+sq kernel (unchanged from r14/r15) ----------------
// Split layout per 64-row band: [chunk 16][sub 4][r16 16][phys-granule 4][8k] f16.
// Granule g holds k = g*8..g*8+7; physical slot = g ^ ((r16>>1)&3).
__global__ __launch_bounds__(256) void split_kernel(
    const float* __restrict__ fa, const float* __restrict__ fb,
    _Float16* __restrict__ ha0, _Float16* __restrict__ ha1,
    _Float16* __restrict__ hb0, _Float16* __restrict__ hb1,
    double* __restrict__ ws)
{
  const int wave = threadIdx.x >> 6, lane = threadIdx.x & 63;
  const int row = blockIdx.x * 4 + wave;
  const float* src = blockIdx.y ? fb : fa;
  _Float16* o0 = blockIdx.y ? hb0 : ha0;
  _Float16* o1 = blockIdx.y ? hb1 : ha1;
  double*  dst = blockIdx.y ? (ws + WS_SQB) : (ws + WS_SQA);

  // sq: exact replica of the original sq_kernel (order-frozen)
  {
    const f32x4* p = (const f32x4*)(src + (size_t)row * DIM);
    double s = 0.0;
#pragma unroll
    for (int c = 0; c < DIM / 4 / 64; ++c) {
      f32x4 v = p[lane + c * 64];
      s += (double)v[0]*v[0] + (double)v[1]*v[1] + (double)v[2]*v[2] + (double)v[3]*v[3];
    }
    for (int off = 32; off; off >>= 1) s += __shfl_down(s, off);
    if (lane == 0) dst[row] = s;
  }

  const int band = row >> 6, sub = (row >> 4) & 3, r16 = row & 15;
  const int c = lane >> 2, g = lane & 3;

  const f32x4* p = (const f32x4*)(src + (size_t)row * DIM + lane * 8);
  f32x4 v0 = p[0], v1 = p[1];

  f16x8 h0, h1;
#pragma unroll
  for (int u = 0; u < 4; ++u) {
    float x = v0[u];
    _Float16 h = (_Float16)x;                          // RNE
    h0[u] = h;
    h1[u] = (_Float16)((x - (float)h) * 2048.0f);      // scaled residual
    float y = v1[u];
    _Float16 hh = (_Float16)y;
    h0[u + 4] = hh;
    h1[u + 4] = (_Float16)((y - (float)hh) * 2048.0f);
  }
  const size_t base = ((size_t)(band * 16 + c) * 4 + sub) * 512 + (size_t)r16 * 32;
  const int gp = (g ^ ((r16 >> 1) & 3)) * 8;
  *(f16x8*)(o0 + base + gp) = h0;
  *(f16x8*)(o1 + base + gp) = h1;
}

// ---------------- MFMA gram, direct-global fragments (no LDS staging) -------------
// 256 threads = 4 waves: mat = wave>>1 (0:A,1:B), h = wave&1 (row-half).
// Wave computes rows h*32..h*32+31 x all 64 cols = 2x4 MFMA 16x16 C-tiles.
// Fragments read DIRECTLY from the split arrays (each read = coalesced 1KB wave
// read of one [sub][r16][granule] row-block; supertile map keeps them L2-hot).
// No k-loop barriers. Frag bytes + per-(i,j) MFMA order identical to r15 ->
// accM/accC bit-identical. G = accM + accC/2048; d2 = si+sj-2G (f64);
// d = fp16_rne((float)sqrt(d2)); diag forced 0.
__global__ void __launch_bounds__(256, 3)
gram_kernel(const _Float16* __restrict__ HA0, const _Float16* __restrict__ HA1,
            const _Float16* __restrict__ HB0, const _Float16* __restrict__ HB1,
            double* __restrict__ ws)
{
  int bi, bj; map_tile(blockIdx.x, bi, bj);
  const int i0 = bi * 64, j0 = bj * 64;
  const bool diag = (bi == bj);

  __shared__ unsigned short db[2][64][32];   // B-waves publish fp16 bits (8 KB)
  __shared__ double wred[4][2];

  const int t = threadIdx.x, wave = t >> 6, lane = t & 63;
  const int mat = wave >> 1, h = wave & 1;
  const int cq = lane & 15, rq = lane >> 4;

  const _Float16* S0 = mat ? HB0 : HA0;
  const _Float16* S1 = mat ? HB1 : HA1;

  // per-lane fragment offset within a [sub] 512-f16 row-block (r15's fo)
  const int laneoff = cq * 32 + ((rq ^ ((cq >> 1) & 3)) << 3);

  const _Float16* pA0 = S0 + ((size_t)(bi * 16) * 4 + h * 2) * 512 + laneoff;
  const _Float16* pA1 = S1 + ((size_t)(bi * 16) * 4 + h * 2) * 512 + laneoff;
  const _Float16* pB0 = S0 + ((size_t)(bj * 16) * 4) * 512 + laneoff;
  const _Float16* pB1 = S1 + ((size_t)(bj * 16) * 4) * 512 + laneoff;

  f32x4 accM[2][4], accC[2][4];
#pragma unroll
  for (int a = 0; a < 2; ++a)
#pragma unroll
    for (int b = 0; b < 4; ++b) { accM[a][b] = (f32x4){0,0,0,0}; accC[a][b] = (f32x4){0,0,0,0}; }

#pragma unroll 1
  for (int c = 0; c < 16; ++c) {
    f16x8 A0[2], A1[2];
#pragma unroll
    for (int ti = 0; ti < 2; ++ti) {
      A0[ti] = *(const f16x8*)(pA0 + ti * 512);
      A1[ti] = *(const f16x8*)(pA1 + ti * 512);
    }
#pragma unroll
    for (int tj = 0; tj < 4; ++tj) {
      f16x8 B0 = *(const f16x8*)(pB0 + tj * 512);
      f16x8 B1 = *(const f16x8*)(pB1 + tj * 512);
#pragma unroll
      for (int ti = 0; ti < 2; ++ti) {
        accM[ti][tj] = __builtin_amdgcn_mfma_f32_16x16x32_f16(A0[ti], B0, accM[ti][tj], 0, 0, 0);
        accC[ti][tj] = __builtin_amdgcn_mfma_f32_16x16x32_f16(A0[ti], B1, accC[ti][tj], 0, 0, 0);
        accC[ti][tj] = __builtin_amdgcn_mfma_f32_16x16x32_f16(A1[ti], B0, accC[ti][tj], 0, 0, 0);
      }
    }
    pA0 += 2048; pA1 += 2048; pB0 += 2048; pB1 += 2048;
  }

  // ---- epilogue: fp16 distances + stats. C/D layout (m89): col=cq, row=rq*4+r.
  const double* sqx = ws + (mat ? WS_SQB : WS_SQA);
  double*       uxp = ws + (mat ? WS_U_B : WS_U_A);

  double si[8], sj[4];
#pragma unroll
  for (int ti = 0; ti < 2; ++ti)
#pragma unroll
    for (int r = 0; r < 4; ++r)
      si[ti * 4 + r] = sqx[i0 + h * 32 + ti * 16 + rq * 4 + r];
#pragma unroll
  for (int tj = 0; tj < 4; ++tj) sj[tj] = sqx[j0 + tj * 16 + cq];

  double rs[8] = {0,0,0,0,0,0,0,0}, cs[4] = {0,0,0,0}, self = 0.0;
  unsigned short pk[2][4][4];

#pragma unroll
  for (int ti = 0; ti < 2; ++ti)
#pragma unroll
    for (int tj = 0; tj < 4; ++tj)
#pragma unroll
      for (int r = 0; r < 4; ++r) {
        double G = (double)accM[ti][tj][r] + (double)accC[ti][tj][r] * (1.0 / 2048.0);
        double d2 = si[ti * 4 + r] + sj[tj] - 2.0 * G;
        unsigned short bits = 0;
        double dq = 0.0;
        if (d2 > 0.0) {
          float df = (float)sqrt(d2);
          __half hh = __float2half(df);          // RNE -- frozen quantization
          bits = __half_as_ushort(hh);
          dq = (double)__half2float(hh);
        }
        if (diag && (h * 32 + ti * 16 + rq * 4 + r == tj * 16 + cq)) { bits = 0; dq = 0.0; }
        pk[ti][tj][r] = bits;
        rs[ti * 4 + r] += dq;
        cs[tj] += dq;
        self += dq * dq;
      }

  if (mat == 1) {
#pragma unroll
    for (int ti = 0; ti < 2; ++ti)
#pragma unroll
      for (int tj = 0; tj < 4; ++tj) {
        u16x4 v = {pk[ti][tj][0], pk[ti][tj][1], pk[ti][tj][2], pk[ti][tj][3]};
        *(u16x4*)(&db[h][lane][(ti * 4 + tj) * 4]) = v;
      }
  }

  // row sums -> u[i0 + h*32 + ti*16 + rq*4 + r]: reduce over cq (xor 1,2,4,8)
#pragma unroll
  for (int z = 0; z < 8; ++z) {
    double v = rs[z];
    v += __shfl_xor(v, 1); v += __shfl_xor(v, 2); v += __shfl_xor(v, 4); v += __shfl_xor(v, 8);
    if (cq == 0) atomicAdd(&uxp[i0 + h * 32 + (z >> 2) * 16 + rq * 4 + (z & 3)], v);
  }
  if (!diag) {  // col sums -> u[j0 + tj*16 + cq]: reduce over rq (xor 16,32); 2 halves add
#pragma unroll
    for (int tj = 0; tj < 4; ++tj) {
      double v = cs[tj];
      v += __shfl_xor(v, 16); v += __shfl_xor(v, 32);
      if (lane < 16) atomicAdd(&uxp[j0 + tj * 16 + cq], v);
    }
  }

  __syncthreads();   // db fully written

  double pab = 0.0;
  if (mat == 0) {
#pragma unroll
    for (int ti = 0; ti < 2; ++ti)
#pragma unroll
      for (int tj = 0; tj < 4; ++tj) {
        u16x4 vb = *(const u16x4*)(&db[h][lane][(ti * 4 + tj) * 4]);
#pragma unroll
        for (int r = 0; r < 4; ++r)
          pab += (double)__half2float(__ushort_as_half(pk[ti][tj][r]))
               * (double)__half2float(__ushort_as_half(vb[r]));
      }
  }

  for (int off = 32; off; off >>= 1) {
    pab  += __shfl_down(pab, off);
    self += __shfl_down(self, off);
  }
  if (lane == 0) {
    wred[wave][0] = (mat == 0) ? pab  : self;   // waves 0,1: pab halves; 2,3: pbb halves
    wred[wave][1] = (mat == 0) ? self : 0.0;    // waves 0,1: paa halves
  }
  __syncthreads();
  if (t == 0) {
    double w = diag ? 1.0 : 2.0;
    ws[WS_PAB + blockIdx.x] = w * (wred[0][0] + wred[1][0]);
    ws[WS_PAA + blockIdx.x] = w * (wred[0][1] + wred[1][1]);
    ws[WS_PBB + blockIdx.x] = w * (wred[2][0] + wred[3][0]);
  }
}

// ---------------- final: reduce stats, closed-form U-centered dots --------------------
__global__ __launch_bounds__(256) void final_kernel(const double* __restrict__ ws,
                                                    float* __restrict__ out)
{
  const int t = threadIdx.x;
  double sa = 0, sb = 0, uab = 0, uaa = 0, ubb = 0, ab = 0, aa = 0, bb = 0;
  for (int i = t; i < NPTS; i += 256) {
    double a = ws[WS_U_A + i], b = ws[WS_U_B + i];
    sa += a; sb += b; uab += a * b; uaa += a * a; ubb += b * b;
  }
  for (int i = t; i < NTILES; i += 256) {
    ab += ws[WS_PAB + i]; aa += ws[WS_PAA + i]; bb += ws[WS_PBB + i];
  }
  for (int off = 32; off; off >>= 1) {
    sa  += __shfl_down(sa, off);  sb  += __shfl_down(sb, off);
    uab += __shfl_down(uab, off); uaa += __shfl_down(uaa, off); ubb += __shfl_down(ubb, off);
    ab  += __shfl_down(ab, off);  aa  += __shfl_down(aa, off);  bb  += __shfl_down(bb, off);
  }
  __shared__ double red[4][8];
  int wave = t >> 6, lane = t & 63;
  if (lane == 0) {
    red[wave][0] = sa;  red[wave][1] = sb;  red[wave][2] = uab; red[wave][3] = uaa;
    red[wave][4] = ubb; red[wave][5] = ab;  red[wave][6] = aa;  red[wave][7] = bb;
  }
  __syncthreads();
  if (t == 0) {
    double v[8] = {0,0,0,0,0,0,0,0};
    for (int qq = 0; qq < 4; ++qq) for (int z = 0; z < 8; ++z) v[z] += red[qq][z];
    const double SA = v[0], SB = v[1], UAB = v[2], UAA = v[3], UBB = v[4];
    const double PAB = v[5], PAA = v[6], PBB = v[7];
    const double n = (double)NPTS, nm2 = n - 2.0;
    auto dotv = [&](double P, double U, double sx, double sy) {
      double tX = sx / ((n - 1.0) * nm2), tY = sy / ((n - 1.0) * nm2);
      double RX = sx / nm2, RY = sy / nm2;
      double su  = U / nm2;
      double srr = U / (nm2 * nm2);
      double full = P - 4.0 * su + tY * sx + tX * sy + 2.0 * n * srr + 2.0 * RX * RY
                  - 2.0 * n * tY * RX - 2.0 * n * tX * RY + n * n * tX * tY;
      double dg = n * tX * tY - 2.0 * tX * RY - 2.0 * tY * RX + 4.0 * srr;
      return full - dg;
    };
    const double denomc = n * (n - 3.0);
    double dab = dotv(PAB, UAB, SA, SB) / denomc;
    double daa = dotv(PAA, UAA, SA, SA) / denomc;
    double dbb = dotv(PBB, UBB, SB, SB) / denomc;
    double dn = sqrt(daa * dbb);
    if (dn < 1e-9) dn = 1e-9;
    out[0] = (float)(dab / dn);
  }
}

extern "C" void kernel_launch(void* const* d_in, const int* in_sizes, int n_in,
                              void* d_out, int out_size, void* d_ws, size_t ws_size,
                              hipStream_t stream) {
  const float* fa = (const float*)d_in[0];
  const float* fb = (const float*)d_in[1];
  double* ws = (double*)d_ws;

  _Float16* HA0 = (_Float16*)((char*)d_ws + WS_F16_BYTE_OFF);
  _Float16* HA1 = HA0 + HELEMS;
  _Float16* HB0 = HA1 + HELEMS;
  _Float16* HB1 = HB0 + HELEMS;

  hipMemsetAsync(d_ws, 0, WS_ZERO_DOUBLES * sizeof(double), stream);
  split_kernel<<<dim3(NPTS / 4, 2), 256, 0, stream>>>(fa, fb, HA0, HA1, HB0, HB1, ws);
  gram_kernel<<<NTILES, 256, 0, stream>>>(HA0, HA1, HB0, HB1, ws);
  final_kernel<<<1, 256, 0, stream>>>(ws, (float*)d_out);
}